// Round 11
// baseline (800.910 us; speedup 1.0000x reference)
//
#include <hip/hip_runtime.h>
#include <math.h>

#define NB 4
#define NWIN 121
#define NBOX (NWIN*NWIN)   /* 14641 */
#define NKEEP 50
#define HWD 256
#define DIM 128
#define HEADS 8
#define NTOK 256
#define NWTOT (NB*NKEEP)   /* 200 */
#define SCPAD 15616        /* 122 rows x 128 cols, swizzled, per batch */

/* ws layout (float units) — proven R8 layout, no extra buffers */
#define OFF_ENT   0          /* 65536 */
#define OFF_SCORE 65536      /* NB*SCPAD = 62464 */
#define OFF_KEEP  128128     /* 100 floats */
#define OFF_WQKV  128256     /* 98304 f */
#define OFF_WOUT  226560     /* 32768 f */
#define OFF_TOKBF 259328     /* 3276800 f */
#define OFF_PO    3536128    /* 3276800 f */
#define WS_FLOATS 6812928    /* 27.3 MB — proven */

#define KP3 68               /* Kh/QP row stride (136B: 8B-aligned, 2-way) */
#define VP3 132              /* VTh row stride (264B: 8B-aligned, 2-way) */

typedef __attribute__((ext_vector_type(8))) short short8;
typedef __attribute__((ext_vector_type(4))) short short4v;
typedef __attribute__((ext_vector_type(4))) float f32x4;

static __device__ __forceinline__ unsigned short f2bf(float f) {
  union { float f; unsigned u; } v; v.f = f;
  unsigned r = (v.u + 0x7fffu + ((v.u >> 16) & 1u)) >> 16;
  return (unsigned short)r;
}
static __device__ __forceinline__ short4v pk4(f32x4 a) {
  short4v r;
  r[0] = (short)f2bf(a[0]); r[1] = (short)f2bf(a[1]);
  r[2] = (short)f2bf(a[2]); r[3] = (short)f2bf(a[3]);
  return r;
}
static __device__ __forceinline__ short8 ld8_lds(const unsigned short* p) {
  short4v a = *(const short4v*)p;
  short4v b = *(const short4v*)(p + 4);
  short8 r;
  r[0]=a[0]; r[1]=a[1]; r[2]=a[2]; r[3]=a[3];
  r[4]=b[0]; r[5]=b[1]; r[6]=b[2]; r[7]=b[3];
  return r;
}
static __device__ __forceinline__ short8 ld8_g(const unsigned short* p) {
  return *(const short8*)p;   /* 16B-aligned global */
}

template<int CTRL>
static __device__ __forceinline__ float dppmax(float v) {
  union { float f; int i; } a, r; a.f = v;
  r.i = __builtin_amdgcn_update_dpp(a.i, a.i, CTRL, 0xf, 0xf, false);
  return fmaxf(v, r.f);
}
static __device__ __forceinline__ float wavemax(float v) {
  v = dppmax<0x111>(v); v = dppmax<0x112>(v);
  v = dppmax<0x114>(v); v = dppmax<0x118>(v);
  v = dppmax<0x142>(v); v = dppmax<0x143>(v);
  union { float f; int i; } gi, gm; gi.f = v;
  gm.i = __builtin_amdgcn_readlane(gi.i, 63);
  return gm.f;
}

__global__ void k_entropy(const float* __restrict__ prob, float* __restrict__ ent) {
  int idx = blockIdx.x * 256 + threadIdx.x;
  int b = idx >> 14, p = idx & 16383;
  float p0 = prob[(size_t)(b * 2) * 16384 + p];
  float p1 = prob[(size_t)(b * 2 + 1) * 16384 + p];
  ent[idx] = -(p0 * log2f(p0 + 1e-10f) + p1 * log2f(p1 + 1e-10f));
}

__global__ void k_score(const float* __restrict__ ent, const float* __restrict__ fw,
                        float* __restrict__ scp) {
  int gid = blockIdx.x * 256 + threadIdx.x;
  if (gid >= NB * SCPAD) return;
  int b = gid / SCPAD, idx = gid % SCPAD;
  int r = idx >> 7, c = idx & 127;
  float s = -INFINITY;
  if (r < NWIN && c < NWIN) {
    const float* e = ent + b * 16384 + r * 128 + c;
    float a = 0.f;
#pragma unroll
    for (int rr = 0; rr < 8; ++rr)
#pragma unroll
      for (int cc = 0; cc < 8; ++cc)
        a += e[rr * 128 + cc] * fw[rr * 8 + cc];
    s = a * (1.0f / 64.0f);
  }
  scp[b * SCPAD + (r << 7) + (c ^ ((r & 7) << 2))] = s;
}

/* Single-wave NMS v4 (proven R8). */
__global__ void k_nms(const float* __restrict__ scp, int* __restrict__ keep) {
  __shared__ float sc[SCPAD];
  int b = blockIdx.x, l = threadIdx.x;
  const float* src = scp + b * SCPAD;
  for (int cb = 0; cb < 64; cb += 8) {
    f32x4 t[8];
#pragma unroll
    for (int i = 0; i < 8; ++i) {
      int idx = (cb + i) * 256 + l * 4;
      if (idx < SCPAD) t[i] = *(const f32x4*)&src[idx];
    }
#pragma unroll
    for (int i = 0; i < 8; ++i) {
      int idx = (cb + i) * 256 + l * 4;
      if (idx < SCPAD) *(f32x4*)&sc[idx] = t[i];
    }
  }
  float M0 = -INFINITY, M1 = -INFINITY; int C0 = 0, C1 = 0;
#pragma unroll
  for (int slot = 0; slot < 2; ++slot) {
    int r = l + slot * 64;
    if (slot == 1 && r >= NWIN) break;
    int r7 = (r & 7) << 2, rbase = r << 7;
    float bv0=-INFINITY,bv1=-INFINITY,bv2=-INFINITY,bv3=-INFINITY;
    int bc0=0,bc1=0,bc2=0,bc3=0;
    for (int lb = 0; lb < 32; ++lb) {
      f32x4 v = *(const f32x4*)&sc[rbase + ((lb << 2) ^ r7)];
      int c0 = lb << 2;
      if (v[0] > bv0) { bv0 = v[0]; bc0 = c0; }
      if (v[1] > bv1) { bv1 = v[1]; bc1 = c0 + 1; }
      if (v[2] > bv2) { bv2 = v[2]; bc2 = c0 + 2; }
      if (v[3] > bv3) { bv3 = v[3]; bc3 = c0 + 3; }
    }
    float bv = bv0; int bc = bc0;
    if (bv1 > bv || (bv1 == bv && bc1 < bc)) { bv = bv1; bc = bc1; }
    if (bv2 > bv || (bv2 == bv && bc2 < bc)) { bv = bv2; bc = bc2; }
    if (bv3 > bv || (bv3 == bv && bc3 < bc)) { bv = bv3; bc = bc3; }
    if (slot == 0) { M0 = bv; C0 = bc; } else { M1 = bv; C1 = bc; }
  }
  for (int k = 0; k < NKEEP; ++k) {
    float gmax = wavemax(fmaxf(M0, M1));
    unsigned long long b0 = __ballot(M0 == gmax);
    unsigned long long b1 = __ballot(M1 == gmax);
    int R;
    if (b0) R = __ffsll((unsigned long long)b0) - 1;
    else    R = 64 + __ffsll((unsigned long long)b1) - 1;
    int Cc = (R < 64) ? __builtin_amdgcn_readlane(C0, R)
                      : __builtin_amdgcn_readlane(C1, R - 64);
    if (l == 0) {
      keep[(b * NKEEP + k) * 2 + 0] = 2 * R;
      keep[(b * NKEEP + k) * 2 + 1] = 2 * Cc;
    }
    bool kill0 = false, kill1 = false;
    {
      int dy = l - R, ady = dy < 0 ? -dy : dy;
      if (ady <= 4) {
        int ih = 15 - 2 * ady;
#pragma unroll
        for (int dx = -4; dx <= 4; ++dx) {
          int adx = dx < 0 ? -dx : dx;
          if ((15 - 2 * adx) * ih > 75) {
            int cc = Cc + dx;
            if ((unsigned)cc < (unsigned)NWIN)
              sc[(l << 7) + (cc ^ ((l & 7) << 2))] = -INFINITY;
          }
        }
        int adx = C0 - Cc; adx = adx < 0 ? -adx : adx;
        kill0 = (adx <= 4) && ((15 - 2 * adx) * ih > 75);
      }
    }
    if (l + 64 < NWIN) {
      int r1 = l + 64;
      int dy = r1 - R, ady = dy < 0 ? -dy : dy;
      if (ady <= 4) {
        int ih = 15 - 2 * ady;
#pragma unroll
        for (int dx = -4; dx <= 4; ++dx) {
          int adx = dx < 0 ? -dx : dx;
          if ((15 - 2 * adx) * ih > 75) {
            int cc = Cc + dx;
            if ((unsigned)cc < (unsigned)NWIN)
              sc[(r1 << 7) + (cc ^ ((r1 & 7) << 2))] = -INFINITY;
          }
        }
        int adx = C1 - Cc; adx = adx < 0 ? -adx : adx;
        kill1 = (adx <= 4) && ((15 - 2 * adx) * ih > 75);
      }
    }
    unsigned long long need0 = __ballot(kill0);
    unsigned long long need1 = __ballot(kill1);
    while (need0 | need1) {
      int rr;
      if (need0) { rr = __ffsll((unsigned long long)need0) - 1; need0 &= need0 - 1; }
      else       { rr = __ffsll((unsigned long long)need1) - 1 + 64; need1 &= need1 - 1; }
      int r7 = (rr & 7) << 2, rbase = rr << 7;
      float v0 = sc[rbase + (l ^ r7)];
      float v1 = sc[rbase + ((l + 64) ^ r7)];
      float rmax = wavemax(fmaxf(v0, v1));
      unsigned long long e0 = __ballot(v0 == rmax);
      unsigned long long e1 = __ballot(v1 == rmax);
      int bc;
      if (e0) bc = __ffsll((unsigned long long)e0) - 1;
      else    bc = 64 + __ffsll((unsigned long long)e1) - 1;
      if (l == (rr & 63)) {
        if (rr >= 64) { M1 = rmax; C1 = bc; }
        else          { M0 = rmax; C0 = bc; }
      }
    }
  }
}

__global__ void k_wcvt(const float* __restrict__ wqkv, const float* __restrict__ wout,
                       unsigned short* __restrict__ wqkv_bf, unsigned short* __restrict__ wout_bf) {
  int i = blockIdx.x * 256 + threadIdx.x;
  if (i < 196608) wqkv_bf[i] = f2bf(wqkv[i]);
  int j = i - 196608;
  if (j >= 0 && j < 65536) wout_bf[j] = f2bf(wout[j]);
}

__global__ void k_toks(const float* __restrict__ x, const int* __restrict__ keep,
                       unsigned short* __restrict__ tokbf) {
  int w = blockIdx.x;
  int b = w / NKEEP;
  int sy = keep[w * 2 + 0], sx = keep[w * 2 + 1];
  int tid = threadIdx.x;
  int ch = tid & 127, th = tid >> 7;
  const float* xb = x + (size_t)b * 65536 * DIM;
  for (int it = 0; it < 128; ++it) {
    int tk = it * 2 + th;
    int i = tk >> 4, j = tk & 15;
    float offy = (i + 0.5f) * 0.9375f;
    float offx = (j + 0.5f) * 0.9375f;
    int li = (int)offy, lj = (int)offx;
    float fy = offy - (float)li, fx = offx - (float)lj;
    const float* p = xb + ((size_t)((sy + li) * HWD + (sx + lj))) * DIM + ch;
    float v00 = p[0], v01 = p[DIM], v10 = p[HWD * DIM], v11 = p[HWD * DIM + DIM];
    float w00 = (1.f - fy) * (1.f - fx), w01 = (1.f - fy) * fx;
    float w10 = fy * (1.f - fx), w11 = fy * fx;
    tokbf[((size_t)w * NTOK + tk) * DIM + ch] = f2bf(w00 * v00 + w01 * v01 + w10 * v10 + w11 * v11);
  }
}

/* ===== Fused attention v3: grid (win, q-half) = 400, 8 waves x 16 queries.
   R8 dataflow (toks->L2-resident reads, proj fused, po only write) with
   half-K staging so LDS = 50.5 KB -> 2 blocks/CU for cross-block overlap.
   Keys ascend in the same 64-chunks as R8 -> identical arithmetic. ===== */
__global__ __launch_bounds__(512, 4) void k_attn3(
    const unsigned short* __restrict__ tokbf,
    const unsigned short* __restrict__ wqkv,
    const unsigned short* __restrict__ wout,
    unsigned short* __restrict__ po) {
  __shared__ __align__(16) char smem[51712];
  unsigned short* Kh  = (unsigned short*)smem;               /* [128][KP3] key-local major */
  unsigned short* VTh = (unsigned short*)(smem + 17408);     /* [64][VP3] d major */
  const int tid = threadIdx.x;
  const int wv = tid >> 6, ln = tid & 63, lo = ln & 15, hi = ln >> 4;
  const int bid = blockIdx.x;
  const int win = bid >> 1, qh = bid & 1;
  unsigned short* QP = (unsigned short*)(smem + 34304 + wv * 2176);  /* [16][KP3] */
  const unsigned short* tw = tokbf + (size_t)win * NTOK * DIM;
  const int qb = qh * 128 + wv * 16;    /* this wave's 16 queries */

  f32x4 pacc[8];
#pragma unroll
  for (int mf = 0; mf < 8; ++mf) pacc[mf] = (f32x4){0.f,0.f,0.f,0.f};

  for (int h = 0; h < HEADS; ++h) {
    /* Q stage (wave-private QP; same-wave in-order vs prev head's proj reads) */
    {
      f32x4 qacc[4];
#pragma unroll
      for (int mf = 0; mf < 4; ++mf) qacc[mf] = (f32x4){0.f,0.f,0.f,0.f};
#pragma unroll
      for (int kf = 0; kf < 4; ++kf) {
        short8 aw[4], bt;
#pragma unroll
        for (int mf = 0; mf < 4; ++mf)
          aw[mf] = ld8_g(wqkv + (size_t)(h * 64 + mf * 16 + lo) * 128 + kf * 32 + hi * 8);
        bt = ld8_g(&tw[(qb + lo) * 128 + kf * 32 + hi * 8]);
#pragma unroll
        for (int mf = 0; mf < 4; ++mf)
          qacc[mf] = __builtin_amdgcn_mfma_f32_16x16x32_bf16(aw[mf], bt, qacc[mf], 0, 0, 0);
      }
#pragma unroll
      for (int mf = 0; mf < 4; ++mf)
        *(short4v*)&QP[lo * KP3 + mf * 16 + hi * 4] = pk4(qacc[mf] * 0.125f);
    }
    short8 Qb[2];
#pragma unroll
    for (int kf = 0; kf < 2; ++kf)
      Qb[kf] = ld8_lds(&QP[lo * KP3 + kf * 32 + hi * 8]);

    f32x4 Ot[4];
#pragma unroll
    for (int mf = 0; mf < 4; ++mf) Ot[mf] = (f32x4){0.f,0.f,0.f,0.f};
    float mrow = -INFINITY, lrow = 0.f;

    for (int half = 0; half < 2; ++half) {
      __syncthreads();            /* all waves done reading Kh/VTh */
      const int kbase = half * 128 + wv * 16;   /* wave's 16-key strip */
      /* K stage: Kh[key_local][d] */
      {
        f32x4 kacc[4];
#pragma unroll
        for (int mf = 0; mf < 4; ++mf) kacc[mf] = (f32x4){0.f,0.f,0.f,0.f};
#pragma unroll
        for (int kf = 0; kf < 4; ++kf) {
          short8 aw[4], bt;
#pragma unroll
          for (int mf = 0; mf < 4; ++mf)
            aw[mf] = ld8_g(wqkv + (size_t)(512 + h * 64 + mf * 16 + lo) * 128 + kf * 32 + hi * 8);
          bt = ld8_g(&tw[(kbase + lo) * 128 + kf * 32 + hi * 8]);
#pragma unroll
          for (int mf = 0; mf < 4; ++mf)
            kacc[mf] = __builtin_amdgcn_mfma_f32_16x16x32_bf16(aw[mf], bt, kacc[mf], 0, 0, 0);
        }
#pragma unroll
        for (int mf = 0; mf < 4; ++mf)
          *(short4v*)&Kh[(wv * 16 + lo) * KP3 + mf * 16 + hi * 4] = pk4(kacc[mf]);
      }
      /* V stage: VTh[d][key_local] */
      {
        f32x4 vacc[4];
#pragma unroll
        for (int nf = 0; nf < 4; ++nf) vacc[nf] = (f32x4){0.f,0.f,0.f,0.f};
#pragma unroll
        for (int kf = 0; kf < 4; ++kf) {
          short8 at, bw[4];
          at = ld8_g(&tw[(kbase + lo) * 128 + kf * 32 + hi * 8]);
#pragma unroll
          for (int nf = 0; nf < 4; ++nf)
            bw[nf] = ld8_g(wqkv + (size_t)(1024 + h * 64 + nf * 16 + lo) * 128 + kf * 32 + hi * 8);
#pragma unroll
          for (int nf = 0; nf < 4; ++nf)
            vacc[nf] = __builtin_amdgcn_mfma_f32_16x16x32_bf16(at, bw[nf], vacc[nf], 0, 0, 0);
        }
#pragma unroll
        for (int nf = 0; nf < 4; ++nf)
          *(short4v*)&VTh[(nf * 16 + lo) * VP3 + wv * 16 + hi * 4] = pk4(vacc[nf]);
      }
      __syncthreads();            /* Kh/VTh visible */

      for (int ck = 0; ck < 2; ++ck) {     /* keys ascend globally */
        f32x4 sacc[4];
#pragma unroll
        for (int mf = 0; mf < 4; ++mf) sacc[mf] = (f32x4){0.f,0.f,0.f,0.f};
        short8 ka[4][2];
#pragma unroll
        for (int mf = 0; mf < 4; ++mf)
#pragma unroll
          for (int kf = 0; kf < 2; ++kf)
            ka[mf][kf] = ld8_lds(&Kh[(ck * 64 + mf * 16 + lo) * KP3 + kf * 32 + hi * 8]);
#pragma unroll
        for (int mf = 0; mf < 4; ++mf)
#pragma unroll
          for (int kf = 0; kf < 2; ++kf)
            sacc[mf] = __builtin_amdgcn_mfma_f32_16x16x32_bf16(ka[mf][kf], Qb[kf], sacc[mf], 0, 0, 0);

        float cmax = -INFINITY;
#pragma unroll
        for (int mf = 0; mf < 4; ++mf)
#pragma unroll
          for (int r = 0; r < 4; ++r) cmax = fmaxf(cmax, sacc[mf][r]);
        cmax = fmaxf(cmax, __shfl_xor(cmax, 16));
        cmax = fmaxf(cmax, __shfl_xor(cmax, 32));
        float mnew = fmaxf(mrow, cmax);
        float corr = __expf(mrow - mnew);
        float ps = 0.f;
#pragma unroll
        for (int mf = 0; mf < 4; ++mf)
#pragma unroll
          for (int r = 0; r < 4; ++r) {
            float e = __expf(sacc[mf][r] - mnew);
            sacc[mf][r] = e; ps += e;
          }
        ps += __shfl_xor(ps, 16);
        ps += __shfl_xor(ps, 32);
        lrow = lrow * corr + ps;
        mrow = mnew;
#pragma unroll
        for (int mf = 0; mf < 4; ++mf) Ot[mf] *= corr;

#pragma unroll
        for (int mf = 0; mf < 4; ++mf)
          *(short4v*)&QP[lo * KP3 + mf * 16 + hi * 4] = pk4(sacc[mf]);
        short8 pb[2], va[4][2];
#pragma unroll
        for (int kf = 0; kf < 2; ++kf)
          pb[kf] = ld8_lds(&QP[lo * KP3 + kf * 32 + hi * 8]);
#pragma unroll
        for (int mf = 0; mf < 4; ++mf)
#pragma unroll
          for (int kf = 0; kf < 2; ++kf)
            va[mf][kf] = ld8_lds(&VTh[(mf * 16 + lo) * VP3 + ck * 64 + kf * 32 + hi * 8]);
#pragma unroll
        for (int mf = 0; mf < 4; ++mf)
#pragma unroll
          for (int kf = 0; kf < 2; ++kf)
            Ot[mf] = __builtin_amdgcn_mfma_f32_16x16x32_bf16(va[mf][kf], pb[kf], Ot[mf], 0, 0, 0);
      }
    }

    /* O finalize -> QP (wave-private), out-proj accumulate over heads */
    {
      float inv = 1.f / lrow;
#pragma unroll
      for (int mf = 0; mf < 4; ++mf)
        *(short4v*)&QP[lo * KP3 + mf * 16 + hi * 4] = pk4(Ot[mf] * inv);
    }
    short8 Ob[2];
#pragma unroll
    for (int kf = 0; kf < 2; ++kf)
      Ob[kf] = ld8_lds(&QP[lo * KP3 + kf * 32 + hi * 8]);
#pragma unroll
    for (int kf = 0; kf < 2; ++kf) {
      short8 aw[8];
#pragma unroll
      for (int mf = 0; mf < 8; ++mf)
        aw[mf] = ld8_g(wout + (size_t)(mf * 16 + lo) * 512 + h * 64 + kf * 32 + hi * 8);
#pragma unroll
      for (int mf = 0; mf < 8; ++mf)
        pacc[mf] = __builtin_amdgcn_mfma_f32_16x16x32_bf16(aw[mf], Ob[kf], pacc[mf], 0, 0, 0);
    }
  }

#pragma unroll
  for (int mf = 0; mf < 8; ++mf)
    *(short4v*)&po[((size_t)win * NTOK + qb + lo) * 128 + mf * 16 + hi * 4] = pk4(pacc[mf]);
}

/* Gather finalize (proven): thread = (pixel, 32-ch quarter). */
__global__ void k_final(const float* __restrict__ x, const unsigned short* __restrict__ po,
                        const int* __restrict__ keep, const float* __restrict__ bout,
                        float* __restrict__ out) {
  __shared__ int kp[2 * NKEEP];
  int tid = threadIdx.x;
  int gid = blockIdx.x * 256 + tid;
  int chq = gid & 3, pix = gid >> 2;
  int b = pix >> 16, pb = pix & 65535, y = pb >> 8, xx = pb & 255;
  if (tid < 2 * NKEEP) kp[tid] = keep[b * 2 * NKEEP + tid];
  __syncthreads();
  float acc[32];
#pragma unroll
  for (int i = 0; i < 32; ++i) acc[i] = 0.f;
  float cnt = 0.f;
  for (int w = 0; w < NKEEP; ++w) {
    int dy = y - kp[2 * w], dx = xx - kp[2 * w + 1];
    if ((unsigned)dy < 16u && (unsigned)dx < 16u) {
      cnt += 1.f;
      const unsigned short* pp = po + ((size_t)(b * NKEEP + w) * NTOK + dy * 16 + dx) * 128 + chq * 32;
#pragma unroll
      for (int k2 = 0; k2 < 4; ++k2) {
        short8 v = ld8_g(pp + k2 * 8);
#pragma unroll
        for (int j = 0; j < 8; ++j) {
          union { unsigned u; float f; } cv;
          cv.u = ((unsigned)(unsigned short)v[j]) << 16;
          acc[k2 * 8 + j] += cv.f;
        }
      }
    }
  }
  size_t base = (size_t)pix * 128 + chq * 32;
  float inv = 1.f / (cnt + 1e-10f);
#pragma unroll
  for (int i = 0; i < 32; ++i)
    out[base + i] = x[base + i] + (acc[i] + cnt * bout[chq * 32 + i]) * inv;
}

extern "C" void kernel_launch(void* const* d_in, const int* in_sizes, int n_in,
                              void* d_out, int out_size, void* d_ws, size_t ws_size,
                              hipStream_t stream) {
  const float* x    = (const float*)d_in[0];
  const float* prob = (const float*)d_in[1];
  const float* fixw = (const float*)d_in[2];
  const float* wqkv = (const float*)d_in[3];
  const float* wout = (const float*)d_in[4];
  const float* bout = (const float*)d_in[5];
  float* out = (float*)d_out;
  float* ws  = (float*)d_ws;
  if (ws_size < (size_t)WS_FLOATS * 4) return;  /* need >= 27.3 MB */

  float* ent  = ws + OFF_ENT;
  float* scp  = ws + OFF_SCORE;
  int*   keep = (int*)(ws + OFF_KEEP);
  unsigned short* wqkv_bf = (unsigned short*)(ws + OFF_WQKV);
  unsigned short* wout_bf = (unsigned short*)(ws + OFF_WOUT);
  unsigned short* tokbf   = (unsigned short*)(ws + OFF_TOKBF);
  unsigned short* po      = (unsigned short*)(ws + OFF_PO);

  k_entropy<<<256, 256, 0, stream>>>(prob, ent);
  k_score<<<(NB * SCPAD + 255) / 256, 256, 0, stream>>>(ent, fixw, scp);
  k_wcvt<<<1024, 256, 0, stream>>>(wqkv, wout, wqkv_bf, wout_bf);
  k_nms<<<NB, 64, 0, stream>>>(scp, keep);
  k_toks<<<NWTOT, 256, 0, stream>>>(x, keep, tokbf);
  k_attn3<<<NWTOT * 2, 512, 0, stream>>>(tokbf, wqkv_bf, wout_bf, po);
  k_final<<<NB * 65536 * 4 / 256, 256, 0, stream>>>(x, po, keep, bout, out);
}

// Round 12
// 390.936 us; speedup vs baseline: 2.0487x; 2.0487x over previous
//
#include <hip/hip_runtime.h>
#include <math.h>

#define NB 4
#define NWIN 121
#define NBOX (NWIN*NWIN)   /* 14641 */
#define NKEEP 50
#define HWD 256
#define DIM 128
#define HEADS 8
#define NTOK 256
#define NWTOT (NB*NKEEP)   /* 200 */
#define SCPAD 15616        /* 122 rows x 128 cols, swizzled, per batch */

/* ws layout (float units) — proven R8 layout */
#define OFF_ENT   0          /* 65536 */
#define OFF_SCORE 65536      /* NB*SCPAD = 62464 */
#define OFF_KEEP  128128     /* 100 floats */
#define OFF_WQKV  128256     /* 98304 f */
#define OFF_WOUT  226560     /* 32768 f */
#define OFF_TOKBF 259328     /* 3276800 f */
#define OFF_PO    3536128    /* 3276800 f */
#define WS_FLOATS 6812928    /* 27.3 MB — proven */

#define KPAD 76              /* R8 fused-kernel strides */
#define VPAD 268
#define KP3 68               /* k_attn3 strides */
#define VP3 132

typedef __attribute__((ext_vector_type(8))) short short8;
typedef __attribute__((ext_vector_type(4))) short short4v;
typedef __attribute__((ext_vector_type(4))) float f32x4;

static __device__ __forceinline__ unsigned short f2bf(float f) {
  union { float f; unsigned u; } v; v.f = f;
  unsigned r = (v.u + 0x7fffu + ((v.u >> 16) & 1u)) >> 16;
  return (unsigned short)r;
}
static __device__ __forceinline__ short4v pk4(f32x4 a) {
  short4v r;
  r[0] = (short)f2bf(a[0]); r[1] = (short)f2bf(a[1]);
  r[2] = (short)f2bf(a[2]); r[3] = (short)f2bf(a[3]);
  return r;
}
static __device__ __forceinline__ short8 ld8_lds(const unsigned short* p) {
  short4v a = *(const short4v*)p;
  short4v b = *(const short4v*)(p + 4);
  short8 r;
  r[0]=a[0]; r[1]=a[1]; r[2]=a[2]; r[3]=a[3];
  r[4]=b[0]; r[5]=b[1]; r[6]=b[2]; r[7]=b[3];
  return r;
}
static __device__ __forceinline__ short8 ld8_g(const unsigned short* p) {
  return *(const short8*)p;   /* 16B-aligned global */
}

template<int CTRL>
static __device__ __forceinline__ float dppmax(float v) {
  union { float f; int i; } a, r; a.f = v;
  r.i = __builtin_amdgcn_update_dpp(a.i, a.i, CTRL, 0xf, 0xf, false);
  return fmaxf(v, r.f);
}
static __device__ __forceinline__ float wavemax(float v) {
  v = dppmax<0x111>(v); v = dppmax<0x112>(v);
  v = dppmax<0x114>(v); v = dppmax<0x118>(v);
  v = dppmax<0x142>(v); v = dppmax<0x143>(v);
  union { float f; int i; } gi, gm; gi.f = v;
  gm.i = __builtin_amdgcn_readlane(gi.i, 63);
  return gm.f;
}

__global__ void k_entropy(const float* __restrict__ prob, float* __restrict__ ent) {
  int idx = blockIdx.x * 256 + threadIdx.x;
  int b = idx >> 14, p = idx & 16383;
  float p0 = prob[(size_t)(b * 2) * 16384 + p];
  float p1 = prob[(size_t)(b * 2 + 1) * 16384 + p];
  ent[idx] = -(p0 * log2f(p0 + 1e-10f) + p1 * log2f(p1 + 1e-10f));
}

__global__ void k_score(const float* __restrict__ ent, const float* __restrict__ fw,
                        float* __restrict__ scp) {
  int gid = blockIdx.x * 256 + threadIdx.x;
  if (gid >= NB * SCPAD) return;
  int b = gid / SCPAD, idx = gid % SCPAD;
  int r = idx >> 7, c = idx & 127;
  float s = -INFINITY;
  if (r < NWIN && c < NWIN) {
    const float* e = ent + b * 16384 + r * 128 + c;
    float a = 0.f;
#pragma unroll
    for (int rr = 0; rr < 8; ++rr)
#pragma unroll
      for (int cc = 0; cc < 8; ++cc)
        a += e[rr * 128 + cc] * fw[rr * 8 + cc];
    s = a * (1.0f / 64.0f);
  }
  scp[b * SCPAD + (r << 7) + (c ^ ((r & 7) << 2))] = s;
}

/* Single-wave NMS v4 (proven R8). */
__global__ void k_nms(const float* __restrict__ scp, int* __restrict__ keep) {
  __shared__ float sc[SCPAD];
  int b = blockIdx.x, l = threadIdx.x;
  const float* src = scp + b * SCPAD;
  for (int cb = 0; cb < 64; cb += 8) {
    f32x4 t[8];
#pragma unroll
    for (int i = 0; i < 8; ++i) {
      int idx = (cb + i) * 256 + l * 4;
      if (idx < SCPAD) t[i] = *(const f32x4*)&src[idx];
    }
#pragma unroll
    for (int i = 0; i < 8; ++i) {
      int idx = (cb + i) * 256 + l * 4;
      if (idx < SCPAD) *(f32x4*)&sc[idx] = t[i];
    }
  }
  float M0 = -INFINITY, M1 = -INFINITY; int C0 = 0, C1 = 0;
#pragma unroll
  for (int slot = 0; slot < 2; ++slot) {
    int r = l + slot * 64;
    if (slot == 1 && r >= NWIN) break;
    int r7 = (r & 7) << 2, rbase = r << 7;
    float bv0=-INFINITY,bv1=-INFINITY,bv2=-INFINITY,bv3=-INFINITY;
    int bc0=0,bc1=0,bc2=0,bc3=0;
    for (int lb = 0; lb < 32; ++lb) {
      f32x4 v = *(const f32x4*)&sc[rbase + ((lb << 2) ^ r7)];
      int c0 = lb << 2;
      if (v[0] > bv0) { bv0 = v[0]; bc0 = c0; }
      if (v[1] > bv1) { bv1 = v[1]; bc1 = c0 + 1; }
      if (v[2] > bv2) { bv2 = v[2]; bc2 = c0 + 2; }
      if (v[3] > bv3) { bv3 = v[3]; bc3 = c0 + 3; }
    }
    float bv = bv0; int bc = bc0;
    if (bv1 > bv || (bv1 == bv && bc1 < bc)) { bv = bv1; bc = bc1; }
    if (bv2 > bv || (bv2 == bv && bc2 < bc)) { bv = bv2; bc = bc2; }
    if (bv3 > bv || (bv3 == bv && bc3 < bc)) { bv = bv3; bc = bc3; }
    if (slot == 0) { M0 = bv; C0 = bc; } else { M1 = bv; C1 = bc; }
  }
  for (int k = 0; k < NKEEP; ++k) {
    float gmax = wavemax(fmaxf(M0, M1));
    unsigned long long b0 = __ballot(M0 == gmax);
    unsigned long long b1 = __ballot(M1 == gmax);
    int R;
    if (b0) R = __ffsll((unsigned long long)b0) - 1;
    else    R = 64 + __ffsll((unsigned long long)b1) - 1;
    int Cc = (R < 64) ? __builtin_amdgcn_readlane(C0, R)
                      : __builtin_amdgcn_readlane(C1, R - 64);
    if (l == 0) {
      keep[(b * NKEEP + k) * 2 + 0] = 2 * R;
      keep[(b * NKEEP + k) * 2 + 1] = 2 * Cc;
    }
    bool kill0 = false, kill1 = false;
    {
      int dy = l - R, ady = dy < 0 ? -dy : dy;
      if (ady <= 4) {
        int ih = 15 - 2 * ady;
#pragma unroll
        for (int dx = -4; dx <= 4; ++dx) {
          int adx = dx < 0 ? -dx : dx;
          if ((15 - 2 * adx) * ih > 75) {
            int cc = Cc + dx;
            if ((unsigned)cc < (unsigned)NWIN)
              sc[(l << 7) + (cc ^ ((l & 7) << 2))] = -INFINITY;
          }
        }
        int adx = C0 - Cc; adx = adx < 0 ? -adx : adx;
        kill0 = (adx <= 4) && ((15 - 2 * adx) * ih > 75);
      }
    }
    if (l + 64 < NWIN) {
      int r1 = l + 64;
      int dy = r1 - R, ady = dy < 0 ? -dy : dy;
      if (ady <= 4) {
        int ih = 15 - 2 * ady;
#pragma unroll
        for (int dx = -4; dx <= 4; ++dx) {
          int adx = dx < 0 ? -dx : dx;
          if ((15 - 2 * adx) * ih > 75) {
            int cc = Cc + dx;
            if ((unsigned)cc < (unsigned)NWIN)
              sc[(r1 << 7) + (cc ^ ((r1 & 7) << 2))] = -INFINITY;
          }
        }
        int adx = C1 - Cc; adx = adx < 0 ? -adx : adx;
        kill1 = (adx <= 4) && ((15 - 2 * adx) * ih > 75);
      }
    }
    unsigned long long need0 = __ballot(kill0);
    unsigned long long need1 = __ballot(kill1);
    while (need0 | need1) {
      int rr;
      if (need0) { rr = __ffsll((unsigned long long)need0) - 1; need0 &= need0 - 1; }
      else       { rr = __ffsll((unsigned long long)need1) - 1 + 64; need1 &= need1 - 1; }
      int r7 = (rr & 7) << 2, rbase = rr << 7;
      float v0 = sc[rbase + (l ^ r7)];
      float v1 = sc[rbase + ((l + 64) ^ r7)];
      float rmax = wavemax(fmaxf(v0, v1));
      unsigned long long e0 = __ballot(v0 == rmax);
      unsigned long long e1 = __ballot(v1 == rmax);
      int bc;
      if (e0) bc = __ffsll((unsigned long long)e0) - 1;
      else    bc = 64 + __ffsll((unsigned long long)e1) - 1;
      if (l == (rr & 63)) {
        if (rr >= 64) { M1 = rmax; C1 = bc; }
        else          { M0 = rmax; C0 = bc; }
      }
    }
  }
}

__global__ void k_wcvt(const float* __restrict__ wqkv, const float* __restrict__ wout,
                       unsigned short* __restrict__ wqkv_bf, unsigned short* __restrict__ wout_bf) {
  int i = blockIdx.x * 256 + threadIdx.x;
  if (i < 196608) wqkv_bf[i] = f2bf(wqkv[i]);
  int j = i - 196608;
  if (j >= 0 && j < 65536) wout_bf[j] = f2bf(wout[j]);
}

__global__ void k_toks(const float* __restrict__ x, const int* __restrict__ keep,
                       unsigned short* __restrict__ tokbf) {
  int w = blockIdx.x;
  int b = w / NKEEP;
  int sy = keep[w * 2 + 0], sx = keep[w * 2 + 1];
  int tid = threadIdx.x;
  int ch = tid & 127, th = tid >> 7;
  const float* xb = x + (size_t)b * 65536 * DIM;
  for (int it = 0; it < 128; ++it) {
    int tk = it * 2 + th;
    int i = tk >> 4, j = tk & 15;
    float offy = (i + 0.5f) * 0.9375f;
    float offx = (j + 0.5f) * 0.9375f;
    int li = (int)offy, lj = (int)offx;
    float fy = offy - (float)li, fx = offx - (float)lj;
    const float* p = xb + ((size_t)((sy + li) * HWD + (sx + lj))) * DIM + ch;
    float v00 = p[0], v01 = p[DIM], v10 = p[HWD * DIM], v11 = p[HWD * DIM + DIM];
    float w00 = (1.f - fy) * (1.f - fx), w01 = (1.f - fy) * fx;
    float w10 = fy * (1.f - fx), w11 = fy * fx;
    tokbf[((size_t)w * NTOK + tk) * DIM + ch] = f2bf(w00 * v00 + w01 * v01 + w10 * v10 + w11 * v11);
  }
}

/* ===== Candidate: q-split fused attention, launch_bounds(512,2) so the
   compiler does NOT spill (R10/R11 lesson: (512,4) forced 64 VGPRs ->
   ~1GB scratch traffic). If compiled VGPR <= 128, HW residency is
   2 blocks/CU (LDS 50.5 KB) -> cross-block latency overlap. Launcher
   verifies via hipFuncGetAttributes and falls back otherwise. ===== */
__global__ __launch_bounds__(512, 2) void k_attn3(
    const unsigned short* __restrict__ tokbf,
    const unsigned short* __restrict__ wqkv,
    const unsigned short* __restrict__ wout,
    unsigned short* __restrict__ po) {
  __shared__ __align__(16) char smem[51712];
  unsigned short* Kh  = (unsigned short*)smem;               /* [128][KP3] */
  unsigned short* VTh = (unsigned short*)(smem + 17408);     /* [64][VP3] */
  const int tid = threadIdx.x;
  const int wv = tid >> 6, ln = tid & 63, lo = ln & 15, hi = ln >> 4;
  const int bid = blockIdx.x;
  const int win = bid >> 1, qh = bid & 1;
  unsigned short* QP = (unsigned short*)(smem + 34304 + wv * 2176);  /* [16][KP3] */
  const unsigned short* tw = tokbf + (size_t)win * NTOK * DIM;
  const int qb = qh * 128 + wv * 16;

  f32x4 pacc[8];
#pragma unroll
  for (int mf = 0; mf < 8; ++mf) pacc[mf] = (f32x4){0.f,0.f,0.f,0.f};

  for (int h = 0; h < HEADS; ++h) {
    {
      f32x4 qacc[4];
#pragma unroll
      for (int mf = 0; mf < 4; ++mf) qacc[mf] = (f32x4){0.f,0.f,0.f,0.f};
#pragma unroll
      for (int kf = 0; kf < 4; ++kf) {
        short8 aw[4], bt;
#pragma unroll
        for (int mf = 0; mf < 4; ++mf)
          aw[mf] = ld8_g(wqkv + (size_t)(h * 64 + mf * 16 + lo) * 128 + kf * 32 + hi * 8);
        bt = ld8_g(&tw[(qb + lo) * 128 + kf * 32 + hi * 8]);
#pragma unroll
        for (int mf = 0; mf < 4; ++mf)
          qacc[mf] = __builtin_amdgcn_mfma_f32_16x16x32_bf16(aw[mf], bt, qacc[mf], 0, 0, 0);
      }
#pragma unroll
      for (int mf = 0; mf < 4; ++mf)
        *(short4v*)&QP[lo * KP3 + mf * 16 + hi * 4] = pk4(qacc[mf] * 0.125f);
    }
    short8 Qb[2];
#pragma unroll
    for (int kf = 0; kf < 2; ++kf)
      Qb[kf] = ld8_lds(&QP[lo * KP3 + kf * 32 + hi * 8]);

    f32x4 Ot[4];
#pragma unroll
    for (int mf = 0; mf < 4; ++mf) Ot[mf] = (f32x4){0.f,0.f,0.f,0.f};
    float mrow = -INFINITY, lrow = 0.f;

    for (int half = 0; half < 2; ++half) {
      __syncthreads();
      const int kbase = half * 128 + wv * 16;
      {
        f32x4 kacc[4];
#pragma unroll
        for (int mf = 0; mf < 4; ++mf) kacc[mf] = (f32x4){0.f,0.f,0.f,0.f};
#pragma unroll
        for (int kf = 0; kf < 4; ++kf) {
          short8 aw[4], bt;
#pragma unroll
          for (int mf = 0; mf < 4; ++mf)
            aw[mf] = ld8_g(wqkv + (size_t)(512 + h * 64 + mf * 16 + lo) * 128 + kf * 32 + hi * 8);
          bt = ld8_g(&tw[(kbase + lo) * 128 + kf * 32 + hi * 8]);
#pragma unroll
          for (int mf = 0; mf < 4; ++mf)
            kacc[mf] = __builtin_amdgcn_mfma_f32_16x16x32_bf16(aw[mf], bt, kacc[mf], 0, 0, 0);
        }
#pragma unroll
        for (int mf = 0; mf < 4; ++mf)
          *(short4v*)&Kh[(wv * 16 + lo) * KP3 + mf * 16 + hi * 4] = pk4(kacc[mf]);
      }
      {
        f32x4 vacc[4];
#pragma unroll
        for (int nf = 0; nf < 4; ++nf) vacc[nf] = (f32x4){0.f,0.f,0.f,0.f};
#pragma unroll
        for (int kf = 0; kf < 4; ++kf) {
          short8 at, bw[4];
          at = ld8_g(&tw[(kbase + lo) * 128 + kf * 32 + hi * 8]);
#pragma unroll
          for (int nf = 0; nf < 4; ++nf)
            bw[nf] = ld8_g(wqkv + (size_t)(1024 + h * 64 + nf * 16 + lo) * 128 + kf * 32 + hi * 8);
#pragma unroll
          for (int nf = 0; nf < 4; ++nf)
            vacc[nf] = __builtin_amdgcn_mfma_f32_16x16x32_bf16(at, bw[nf], vacc[nf], 0, 0, 0);
        }
#pragma unroll
        for (int nf = 0; nf < 4; ++nf)
          *(short4v*)&VTh[(nf * 16 + lo) * VP3 + wv * 16 + hi * 4] = pk4(vacc[nf]);
      }
      __syncthreads();

      for (int ck = 0; ck < 2; ++ck) {
        f32x4 sacc[4];
#pragma unroll
        for (int mf = 0; mf < 4; ++mf) sacc[mf] = (f32x4){0.f,0.f,0.f,0.f};
        short8 ka[4][2];
#pragma unroll
        for (int mf = 0; mf < 4; ++mf)
#pragma unroll
          for (int kf = 0; kf < 2; ++kf)
            ka[mf][kf] = ld8_lds(&Kh[(ck * 64 + mf * 16 + lo) * KP3 + kf * 32 + hi * 8]);
#pragma unroll
        for (int mf = 0; mf < 4; ++mf)
#pragma unroll
          for (int kf = 0; kf < 2; ++kf)
            sacc[mf] = __builtin_amdgcn_mfma_f32_16x16x32_bf16(ka[mf][kf], Qb[kf], sacc[mf], 0, 0, 0);

        float cmax = -INFINITY;
#pragma unroll
        for (int mf = 0; mf < 4; ++mf)
#pragma unroll
          for (int r = 0; r < 4; ++r) cmax = fmaxf(cmax, sacc[mf][r]);
        cmax = fmaxf(cmax, __shfl_xor(cmax, 16));
        cmax = fmaxf(cmax, __shfl_xor(cmax, 32));
        float mnew = fmaxf(mrow, cmax);
        float corr = __expf(mrow - mnew);
        float ps = 0.f;
#pragma unroll
        for (int mf = 0; mf < 4; ++mf)
#pragma unroll
          for (int r = 0; r < 4; ++r) {
            float e = __expf(sacc[mf][r] - mnew);
            sacc[mf][r] = e; ps += e;
          }
        ps += __shfl_xor(ps, 16);
        ps += __shfl_xor(ps, 32);
        lrow = lrow * corr + ps;
        mrow = mnew;
#pragma unroll
        for (int mf = 0; mf < 4; ++mf) Ot[mf] *= corr;

#pragma unroll
        for (int mf = 0; mf < 4; ++mf)
          *(short4v*)&QP[lo * KP3 + mf * 16 + hi * 4] = pk4(sacc[mf]);
        short8 pb[2], va[4][2];
#pragma unroll
        for (int kf = 0; kf < 2; ++kf)
          pb[kf] = ld8_lds(&QP[lo * KP3 + kf * 32 + hi * 8]);
#pragma unroll
        for (int mf = 0; mf < 4; ++mf)
#pragma unroll
          for (int kf = 0; kf < 2; ++kf)
            va[mf][kf] = ld8_lds(&VTh[(mf * 16 + lo) * VP3 + ck * 64 + kf * 32 + hi * 8]);
#pragma unroll
        for (int mf = 0; mf < 4; ++mf)
#pragma unroll
          for (int kf = 0; kf < 2; ++kf)
            Ot[mf] = __builtin_amdgcn_mfma_f32_16x16x32_bf16(va[mf][kf], pb[kf], Ot[mf], 0, 0, 0);
      }
    }

    {
      float inv = 1.f / lrow;
#pragma unroll
      for (int mf = 0; mf < 4; ++mf)
        *(short4v*)&QP[lo * KP3 + mf * 16 + hi * 4] = pk4(Ot[mf] * inv);
    }
    short8 Ob[2];
#pragma unroll
    for (int kf = 0; kf < 2; ++kf)
      Ob[kf] = ld8_lds(&QP[lo * KP3 + kf * 32 + hi * 8]);
#pragma unroll
    for (int kf = 0; kf < 2; ++kf) {
      short8 aw[8];
#pragma unroll
      for (int mf = 0; mf < 8; ++mf)
        aw[mf] = ld8_g(wout + (size_t)(mf * 16 + lo) * 512 + h * 64 + kf * 32 + hi * 8);
#pragma unroll
      for (int mf = 0; mf < 8; ++mf)
        pacc[mf] = __builtin_amdgcn_mfma_f32_16x16x32_bf16(aw[mf], Ob[kf], pacc[mf], 0, 0, 0);
    }
  }

#pragma unroll
  for (int mf = 0; mf < 8; ++mf)
    *(short4v*)&po[((size_t)win * NTOK + qb + lo) * 128 + mf * 16 + hi * 4] = pk4(pacc[mf]);
}

/* ===== Fallback: proven R8 fused k_attn (182 us, bit-proven) ===== */
__global__ __launch_bounds__(512, 2) void k_attn(
    const unsigned short* __restrict__ tokbf,
    const unsigned short* __restrict__ wqkv,
    const unsigned short* __restrict__ wout,
    unsigned short* __restrict__ po) {
  __shared__ __align__(16) char smem[112128];
  unsigned short* Klds = (unsigned short*)smem;
  unsigned short* VT   = (unsigned short*)(smem + 38912);
  const int tid = threadIdx.x;
  const int wv = tid >> 6, ln = tid & 63;
  const int lo = ln & 15, hi = ln >> 4;
  const int win = blockIdx.x;
  unsigned short* QP = (unsigned short*)(smem + 73216 + wv * 4864);
  const unsigned short* tw = tokbf + (size_t)win * NTOK * DIM;
  const int qrow = wv * 32;

  f32x4 pacc[8][2];
#pragma unroll
  for (int mf = 0; mf < 8; ++mf)
#pragma unroll
    for (int nf = 0; nf < 2; ++nf) pacc[mf][nf] = (f32x4){0.f,0.f,0.f,0.f};

  for (int h = 0; h < HEADS; ++h) {
    if (h) __syncthreads();
    {
      f32x4 kacc[4][2];
#pragma unroll
      for (int mf = 0; mf < 4; ++mf)
#pragma unroll
        for (int nf = 0; nf < 2; ++nf) kacc[mf][nf] = (f32x4){0.f,0.f,0.f,0.f};
#pragma unroll
      for (int kf = 0; kf < 4; ++kf) {
        short8 aw[4], bt[2];
#pragma unroll
        for (int mf = 0; mf < 4; ++mf)
          aw[mf] = ld8_g(wqkv + (size_t)(512 + h * 64 + mf * 16 + lo) * 128 + kf * 32 + hi * 8);
#pragma unroll
        for (int nf = 0; nf < 2; ++nf)
          bt[nf] = ld8_g(&tw[(qrow + nf * 16 + lo) * 128 + kf * 32 + hi * 8]);
#pragma unroll
        for (int mf = 0; mf < 4; ++mf)
#pragma unroll
          for (int nf = 0; nf < 2; ++nf)
            kacc[mf][nf] = __builtin_amdgcn_mfma_f32_16x16x32_bf16(aw[mf], bt[nf], kacc[mf][nf], 0, 0, 0);
      }
#pragma unroll
      for (int mf = 0; mf < 4; ++mf)
#pragma unroll
        for (int nf = 0; nf < 2; ++nf)
          *(short4v*)&Klds[(qrow + nf * 16 + lo) * KPAD + mf * 16 + hi * 4] = pk4(kacc[mf][nf]);
    }
    {
      f32x4 vacc[2][4];
#pragma unroll
      for (int mf = 0; mf < 2; ++mf)
#pragma unroll
        for (int nf = 0; nf < 4; ++nf) vacc[mf][nf] = (f32x4){0.f,0.f,0.f,0.f};
#pragma unroll
      for (int kf = 0; kf < 4; ++kf) {
        short8 at[2], bw[4];
#pragma unroll
        for (int mf = 0; mf < 2; ++mf)
          at[mf] = ld8_g(&tw[(qrow + mf * 16 + lo) * 128 + kf * 32 + hi * 8]);
#pragma unroll
        for (int nf = 0; nf < 4; ++nf)
          bw[nf] = ld8_g(wqkv + (size_t)(1024 + h * 64 + nf * 16 + lo) * 128 + kf * 32 + hi * 8);
#pragma unroll
        for (int mf = 0; mf < 2; ++mf)
#pragma unroll
          for (int nf = 0; nf < 4; ++nf)
            vacc[mf][nf] = __builtin_amdgcn_mfma_f32_16x16x32_bf16(at[mf], bw[nf], vacc[mf][nf], 0, 0, 0);
      }
#pragma unroll
      for (int mf = 0; mf < 2; ++mf)
#pragma unroll
        for (int nf = 0; nf < 4; ++nf)
          *(short4v*)&VT[(nf * 16 + lo) * VPAD + qrow + mf * 16 + hi * 4] = pk4(vacc[mf][nf]);
    }
    {
      f32x4 qacc[4][2];
#pragma unroll
      for (int mf = 0; mf < 4; ++mf)
#pragma unroll
        for (int nf = 0; nf < 2; ++nf) qacc[mf][nf] = (f32x4){0.f,0.f,0.f,0.f};
#pragma unroll
      for (int kf = 0; kf < 4; ++kf) {
        short8 aw[4], bt[2];
#pragma unroll
        for (int mf = 0; mf < 4; ++mf)
          aw[mf] = ld8_g(wqkv + (size_t)(h * 64 + mf * 16 + lo) * 128 + kf * 32 + hi * 8);
#pragma unroll
        for (int nf = 0; nf < 2; ++nf)
          bt[nf] = ld8_g(&tw[(qrow + nf * 16 + lo) * 128 + kf * 32 + hi * 8]);
#pragma unroll
        for (int mf = 0; mf < 4; ++mf)
#pragma unroll
          for (int nf = 0; nf < 2; ++nf)
            qacc[mf][nf] = __builtin_amdgcn_mfma_f32_16x16x32_bf16(aw[mf], bt[nf], qacc[mf][nf], 0, 0, 0);
      }
#pragma unroll
      for (int mf = 0; mf < 4; ++mf)
#pragma unroll
        for (int nf = 0; nf < 2; ++nf)
          *(short4v*)&QP[(nf * 16 + lo) * KPAD + mf * 16 + hi * 4] = pk4(qacc[mf][nf] * 0.125f);
    }
    __syncthreads();

    short8 Qb[2][2];
#pragma unroll
    for (int nf = 0; nf < 2; ++nf)
#pragma unroll
      for (int kf = 0; kf < 2; ++kf)
        Qb[nf][kf] = ld8_lds(&QP[(nf * 16 + lo) * KPAD + kf * 32 + hi * 8]);

    f32x4 Ot[4][2];
#pragma unroll
    for (int mf = 0; mf < 4; ++mf)
#pragma unroll
      for (int nf = 0; nf < 2; ++nf) Ot[mf][nf] = (f32x4){0.f,0.f,0.f,0.f};
    float mrow[2] = {-INFINITY, -INFINITY};
    float lrow[2] = {0.f, 0.f};

    for (int ck = 0; ck < 4; ++ck) {
      f32x4 sacc[4][2];
#pragma unroll
      for (int mf = 0; mf < 4; ++mf)
#pragma unroll
        for (int nf = 0; nf < 2; ++nf) sacc[mf][nf] = (f32x4){0.f,0.f,0.f,0.f};
      short8 ka[4][2];
#pragma unroll
      for (int mf = 0; mf < 4; ++mf)
#pragma unroll
        for (int kf = 0; kf < 2; ++kf)
          ka[mf][kf] = ld8_lds(&Klds[(ck * 64 + mf * 16 + lo) * KPAD + kf * 32 + hi * 8]);
#pragma unroll
      for (int mf = 0; mf < 4; ++mf)
#pragma unroll
        for (int nf = 0; nf < 2; ++nf)
#pragma unroll
          for (int kf = 0; kf < 2; ++kf)
            sacc[mf][nf] = __builtin_amdgcn_mfma_f32_16x16x32_bf16(ka[mf][kf], Qb[nf][kf], sacc[mf][nf], 0, 0, 0);

#pragma unroll
      for (int nf = 0; nf < 2; ++nf) {
        float cmax = -INFINITY;
#pragma unroll
        for (int mf = 0; mf < 4; ++mf)
#pragma unroll
          for (int r = 0; r < 4; ++r) cmax = fmaxf(cmax, sacc[mf][nf][r]);
        cmax = fmaxf(cmax, __shfl_xor(cmax, 16));
        cmax = fmaxf(cmax, __shfl_xor(cmax, 32));
        float mnew = fmaxf(mrow[nf], cmax);
        float corr = __expf(mrow[nf] - mnew);
        float ps = 0.f;
#pragma unroll
        for (int mf = 0; mf < 4; ++mf)
#pragma unroll
          for (int r = 0; r < 4; ++r) {
            float e = __expf(sacc[mf][nf][r] - mnew);
            sacc[mf][nf][r] = e; ps += e;
          }
        ps += __shfl_xor(ps, 16);
        ps += __shfl_xor(ps, 32);
        lrow[nf] = lrow[nf] * corr + ps;
        mrow[nf] = mnew;
#pragma unroll
        for (int mf = 0; mf < 4; ++mf) Ot[mf][nf] *= corr;
      }
#pragma unroll
      for (int mf = 0; mf < 4; ++mf)
#pragma unroll
        for (int nf = 0; nf < 2; ++nf)
          *(short4v*)&QP[(nf * 16 + lo) * KPAD + mf * 16 + hi * 4] = pk4(sacc[mf][nf]);
      short8 pb[2][2], va[4][2];
#pragma unroll
      for (int nf = 0; nf < 2; ++nf)
#pragma unroll
        for (int kf = 0; kf < 2; ++kf)
          pb[nf][kf] = ld8_lds(&QP[(nf * 16 + lo) * KPAD + kf * 32 + hi * 8]);
#pragma unroll
      for (int mf = 0; mf < 4; ++mf)
#pragma unroll
        for (int kf = 0; kf < 2; ++kf)
          va[mf][kf] = ld8_lds(&VT[(mf * 16 + lo) * VPAD + ck * 64 + kf * 32 + hi * 8]);
#pragma unroll
      for (int mf = 0; mf < 4; ++mf)
#pragma unroll
        for (int nf = 0; nf < 2; ++nf)
#pragma unroll
          for (int kf = 0; kf < 2; ++kf)
            Ot[mf][nf] = __builtin_amdgcn_mfma_f32_16x16x32_bf16(va[mf][kf], pb[nf][kf], Ot[mf][nf], 0, 0, 0);
    }

#pragma unroll
    for (int nf = 0; nf < 2; ++nf) {
      float inv = 1.f / lrow[nf];
#pragma unroll
      for (int mf = 0; mf < 4; ++mf)
        *(short4v*)&QP[(nf * 16 + lo) * KPAD + mf * 16 + hi * 4] = pk4(Ot[mf][nf] * inv);
    }
    short8 Ob[2][2];
#pragma unroll
    for (int nf = 0; nf < 2; ++nf)
#pragma unroll
      for (int kf = 0; kf < 2; ++kf)
        Ob[nf][kf] = ld8_lds(&QP[(nf * 16 + lo) * KPAD + kf * 32 + hi * 8]);
#pragma unroll
    for (int kf = 0; kf < 2; ++kf) {
      short8 aw[8];
#pragma unroll
      for (int mf = 0; mf < 8; ++mf)
        aw[mf] = ld8_g(wout + (size_t)(mf * 16 + lo) * 512 + h * 64 + kf * 32 + hi * 8);
#pragma unroll
      for (int mf = 0; mf < 8; ++mf)
#pragma unroll
        for (int nf = 0; nf < 2; ++nf)
          pacc[mf][nf] = __builtin_amdgcn_mfma_f32_16x16x32_bf16(aw[mf], Ob[nf][kf], pacc[mf][nf], 0, 0, 0);
    }
  }
#pragma unroll
  for (int mf = 0; mf < 8; ++mf)
#pragma unroll
    for (int nf = 0; nf < 2; ++nf)
      *(short4v*)&po[((size_t)win * NTOK + qrow + nf * 16 + lo) * 128 + mf * 16 + hi * 4] = pk4(pacc[mf][nf]);
}

/* Gather finalize (proven). */
__global__ void k_final(const float* __restrict__ x, const unsigned short* __restrict__ po,
                        const int* __restrict__ keep, const float* __restrict__ bout,
                        float* __restrict__ out) {
  __shared__ int kp[2 * NKEEP];
  int tid = threadIdx.x;
  int gid = blockIdx.x * 256 + tid;
  int chq = gid & 3, pix = gid >> 2;
  int b = pix >> 16, pb = pix & 65535, y = pb >> 8, xx = pb & 255;
  if (tid < 2 * NKEEP) kp[tid] = keep[b * 2 * NKEEP + tid];
  __syncthreads();
  float acc[32];
#pragma unroll
  for (int i = 0; i < 32; ++i) acc[i] = 0.f;
  float cnt = 0.f;
  for (int w = 0; w < NKEEP; ++w) {
    int dy = y - kp[2 * w], dx = xx - kp[2 * w + 1];
    if ((unsigned)dy < 16u && (unsigned)dx < 16u) {
      cnt += 1.f;
      const unsigned short* pp = po + ((size_t)(b * NKEEP + w) * NTOK + dy * 16 + dx) * 128 + chq * 32;
#pragma unroll
      for (int k2 = 0; k2 < 4; ++k2) {
        short8 v = ld8_g(pp + k2 * 8);
#pragma unroll
        for (int j = 0; j < 8; ++j) {
          union { unsigned u; float f; } cv;
          cv.u = ((unsigned)(unsigned short)v[j]) << 16;
          acc[k2 * 8 + j] += cv.f;
        }
      }
    }
  }
  size_t base = (size_t)pix * 128 + chq * 32;
  float inv = 1.f / (cnt + 1e-10f);
#pragma unroll
  for (int i = 0; i < 32; ++i)
    out[base + i] = x[base + i] + (acc[i] + cnt * bout[chq * 32 + i]) * inv;
}

extern "C" void kernel_launch(void* const* d_in, const int* in_sizes, int n_in,
                              void* d_out, int out_size, void* d_ws, size_t ws_size,
                              hipStream_t stream) {
  const float* x    = (const float*)d_in[0];
  const float* prob = (const float*)d_in[1];
  const float* fixw = (const float*)d_in[2];
  const float* wqkv = (const float*)d_in[3];
  const float* wout = (const float*)d_in[4];
  const float* bout = (const float*)d_in[5];
  float* out = (float*)d_out;
  float* ws  = (float*)d_ws;
  if (ws_size < (size_t)WS_FLOATS * 4) return;  /* need >= 27.3 MB */

  float* ent  = ws + OFF_ENT;
  float* scp  = ws + OFF_SCORE;
  int*   keep = (int*)(ws + OFF_KEEP);
  unsigned short* wqkv_bf = (unsigned short*)(ws + OFF_WQKV);
  unsigned short* wout_bf = (unsigned short*)(ws + OFF_WOUT);
  unsigned short* tokbf   = (unsigned short*)(ws + OFF_TOKBF);
  unsigned short* po      = (unsigned short*)(ws + OFF_PO);

  /* Deterministic host-side check: use the q-split kernel only if the
     compiler kept it spill-free at 2-blocks/CU residency (VGPR <= 128). */
  hipFuncAttributes fa;
  int use3 = 0;
  if (hipFuncGetAttributes(&fa, (const void*)k_attn3) == hipSuccess)
    use3 = (fa.numRegs > 0 && fa.numRegs <= 128 && fa.localSizeBytes == 0);

  k_entropy<<<256, 256, 0, stream>>>(prob, ent);
  k_score<<<(NB * SCPAD + 255) / 256, 256, 0, stream>>>(ent, fixw, scp);
  k_wcvt<<<1024, 256, 0, stream>>>(wqkv, wout, wqkv_bf, wout_bf);
  k_nms<<<NB, 64, 0, stream>>>(scp, keep);
  k_toks<<<NWTOT, 256, 0, stream>>>(x, keep, tokbf);
  if (use3)
    k_attn3<<<NWTOT * 2, 512, 0, stream>>>(tokbf, wqkv_bf, wout_bf, po);
  else
    k_attn<<<NWTOT, 512, 0, stream>>>(tokbf, wqkv_bf, wout_bf, po);
  k_final<<<NB * 65536 * 4 / 256, 256, 0, stream>>>(x, po, keep, bout, out);
}

// Round 13
// 390.716 us; speedup vs baseline: 2.0499x; 1.0006x over previous
//
#include <hip/hip_runtime.h>
#include <math.h>

#define NB 4
#define NWIN 121
#define NBOX (NWIN*NWIN)   /* 14641 */
#define NKEEP 50
#define HWD 256
#define DIM 128
#define HEADS 8
#define NTOK 256
#define NWTOT (NB*NKEEP)   /* 200 */
#define SCPAD 15616        /* 122 rows x 128 cols, swizzled, per batch */

/* ws layout (float units) — proven R8 layout */
#define OFF_ENT   0          /* 65536 */
#define OFF_SCORE 65536      /* NB*SCPAD = 62464 */
#define OFF_KEEP  128128     /* 100 floats */
#define OFF_WQKV  128256     /* 98304 f */
#define OFF_WOUT  226560     /* 32768 f */
#define OFF_TOKBF 259328     /* 3276800 f */
#define OFF_PO    3536128    /* 3276800 f */
#define WS_FLOATS 6812928    /* 27.3 MB — proven */

#define KPAD 76              /* R8 fused-kernel strides */
#define VPAD 268
#define KP3 68               /* k_attn3 strides */
#define VP3 132

typedef __attribute__((ext_vector_type(8))) short short8;
typedef __attribute__((ext_vector_type(4))) short short4v;
typedef __attribute__((ext_vector_type(4))) float f32x4;

static __device__ __forceinline__ unsigned short f2bf(float f) {
  union { float f; unsigned u; } v; v.f = f;
  unsigned r = (v.u + 0x7fffu + ((v.u >> 16) & 1u)) >> 16;
  return (unsigned short)r;
}
static __device__ __forceinline__ short4v pk4(f32x4 a) {
  short4v r;
  r[0] = (short)f2bf(a[0]); r[1] = (short)f2bf(a[1]);
  r[2] = (short)f2bf(a[2]); r[3] = (short)f2bf(a[3]);
  return r;
}
static __device__ __forceinline__ short8 ld8_lds(const unsigned short* p) {
  short4v a = *(const short4v*)p;
  short4v b = *(const short4v*)(p + 4);
  short8 r;
  r[0]=a[0]; r[1]=a[1]; r[2]=a[2]; r[3]=a[3];
  r[4]=b[0]; r[5]=b[1]; r[6]=b[2]; r[7]=b[3];
  return r;
}
static __device__ __forceinline__ short8 ld8_g(const unsigned short* p) {
  return *(const short8*)p;   /* 16B-aligned global */
}

template<int CTRL>
static __device__ __forceinline__ float dppmax(float v) {
  union { float f; int i; } a, r; a.f = v;
  r.i = __builtin_amdgcn_update_dpp(a.i, a.i, CTRL, 0xf, 0xf, false);
  return fmaxf(v, r.f);
}
static __device__ __forceinline__ float wavemax(float v) {
  v = dppmax<0x111>(v); v = dppmax<0x112>(v);
  v = dppmax<0x114>(v); v = dppmax<0x118>(v);
  v = dppmax<0x142>(v); v = dppmax<0x143>(v);
  union { float f; int i; } gi, gm; gi.f = v;
  gm.i = __builtin_amdgcn_readlane(gi.i, 63);
  return gm.f;
}

__global__ void k_entropy(const float* __restrict__ prob, float* __restrict__ ent) {
  int idx = blockIdx.x * 256 + threadIdx.x;
  int b = idx >> 14, p = idx & 16383;
  float p0 = prob[(size_t)(b * 2) * 16384 + p];
  float p1 = prob[(size_t)(b * 2 + 1) * 16384 + p];
  ent[idx] = -(p0 * log2f(p0 + 1e-10f) + p1 * log2f(p1 + 1e-10f));
}

__global__ void k_score(const float* __restrict__ ent, const float* __restrict__ fw,
                        float* __restrict__ scp) {
  int gid = blockIdx.x * 256 + threadIdx.x;
  if (gid >= NB * SCPAD) return;
  int b = gid / SCPAD, idx = gid % SCPAD;
  int r = idx >> 7, c = idx & 127;
  float s = -INFINITY;
  if (r < NWIN && c < NWIN) {
    const float* e = ent + b * 16384 + r * 128 + c;
    float a = 0.f;
#pragma unroll
    for (int rr = 0; rr < 8; ++rr)
#pragma unroll
      for (int cc = 0; cc < 8; ++cc)
        a += e[rr * 128 + cc] * fw[rr * 8 + cc];
    s = a * (1.0f / 64.0f);
  }
  scp[b * SCPAD + (r << 7) + (c ^ ((r & 7) << 2))] = s;
}

/* Single-wave NMS v4 (proven R8). */
__global__ void k_nms(const float* __restrict__ scp, int* __restrict__ keep) {
  __shared__ float sc[SCPAD];
  int b = blockIdx.x, l = threadIdx.x;
  const float* src = scp + b * SCPAD;
  for (int cb = 0; cb < 64; cb += 8) {
    f32x4 t[8];
#pragma unroll
    for (int i = 0; i < 8; ++i) {
      int idx = (cb + i) * 256 + l * 4;
      if (idx < SCPAD) t[i] = *(const f32x4*)&src[idx];
    }
#pragma unroll
    for (int i = 0; i < 8; ++i) {
      int idx = (cb + i) * 256 + l * 4;
      if (idx < SCPAD) *(f32x4*)&sc[idx] = t[i];
    }
  }
  float M0 = -INFINITY, M1 = -INFINITY; int C0 = 0, C1 = 0;
#pragma unroll
  for (int slot = 0; slot < 2; ++slot) {
    int r = l + slot * 64;
    if (slot == 1 && r >= NWIN) break;
    int r7 = (r & 7) << 2, rbase = r << 7;
    float bv0=-INFINITY,bv1=-INFINITY,bv2=-INFINITY,bv3=-INFINITY;
    int bc0=0,bc1=0,bc2=0,bc3=0;
    for (int lb = 0; lb < 32; ++lb) {
      f32x4 v = *(const f32x4*)&sc[rbase + ((lb << 2) ^ r7)];
      int c0 = lb << 2;
      if (v[0] > bv0) { bv0 = v[0]; bc0 = c0; }
      if (v[1] > bv1) { bv1 = v[1]; bc1 = c0 + 1; }
      if (v[2] > bv2) { bv2 = v[2]; bc2 = c0 + 2; }
      if (v[3] > bv3) { bv3 = v[3]; bc3 = c0 + 3; }
    }
    float bv = bv0; int bc = bc0;
    if (bv1 > bv || (bv1 == bv && bc1 < bc)) { bv = bv1; bc = bc1; }
    if (bv2 > bv || (bv2 == bv && bc2 < bc)) { bv = bv2; bc = bc2; }
    if (bv3 > bv || (bv3 == bv && bc3 < bc)) { bv = bv3; bc = bc3; }
    if (slot == 0) { M0 = bv; C0 = bc; } else { M1 = bv; C1 = bc; }
  }
  for (int k = 0; k < NKEEP; ++k) {
    float gmax = wavemax(fmaxf(M0, M1));
    unsigned long long b0 = __ballot(M0 == gmax);
    unsigned long long b1 = __ballot(M1 == gmax);
    int R;
    if (b0) R = __ffsll((unsigned long long)b0) - 1;
    else    R = 64 + __ffsll((unsigned long long)b1) - 1;
    int Cc = (R < 64) ? __builtin_amdgcn_readlane(C0, R)
                      : __builtin_amdgcn_readlane(C1, R - 64);
    if (l == 0) {
      keep[(b * NKEEP + k) * 2 + 0] = 2 * R;
      keep[(b * NKEEP + k) * 2 + 1] = 2 * Cc;
    }
    bool kill0 = false, kill1 = false;
    {
      int dy = l - R, ady = dy < 0 ? -dy : dy;
      if (ady <= 4) {
        int ih = 15 - 2 * ady;
#pragma unroll
        for (int dx = -4; dx <= 4; ++dx) {
          int adx = dx < 0 ? -dx : dx;
          if ((15 - 2 * adx) * ih > 75) {
            int cc = Cc + dx;
            if ((unsigned)cc < (unsigned)NWIN)
              sc[(l << 7) + (cc ^ ((l & 7) << 2))] = -INFINITY;
          }
        }
        int adx = C0 - Cc; adx = adx < 0 ? -adx : adx;
        kill0 = (adx <= 4) && ((15 - 2 * adx) * ih > 75);
      }
    }
    if (l + 64 < NWIN) {
      int r1 = l + 64;
      int dy = r1 - R, ady = dy < 0 ? -dy : dy;
      if (ady <= 4) {
        int ih = 15 - 2 * ady;
#pragma unroll
        for (int dx = -4; dx <= 4; ++dx) {
          int adx = dx < 0 ? -dx : dx;
          if ((15 - 2 * adx) * ih > 75) {
            int cc = Cc + dx;
            if ((unsigned)cc < (unsigned)NWIN)
              sc[(r1 << 7) + (cc ^ ((r1 & 7) << 2))] = -INFINITY;
          }
        }
        int adx = C1 - Cc; adx = adx < 0 ? -adx : adx;
        kill1 = (adx <= 4) && ((15 - 2 * adx) * ih > 75);
      }
    }
    unsigned long long need0 = __ballot(kill0);
    unsigned long long need1 = __ballot(kill1);
    while (need0 | need1) {
      int rr;
      if (need0) { rr = __ffsll((unsigned long long)need0) - 1; need0 &= need0 - 1; }
      else       { rr = __ffsll((unsigned long long)need1) - 1 + 64; need1 &= need1 - 1; }
      int r7 = (rr & 7) << 2, rbase = rr << 7;
      float v0 = sc[rbase + (l ^ r7)];
      float v1 = sc[rbase + ((l + 64) ^ r7)];
      float rmax = wavemax(fmaxf(v0, v1));
      unsigned long long e0 = __ballot(v0 == rmax);
      unsigned long long e1 = __ballot(v1 == rmax);
      int bc;
      if (e0) bc = __ffsll((unsigned long long)e0) - 1;
      else    bc = 64 + __ffsll((unsigned long long)e1) - 1;
      if (l == (rr & 63)) {
        if (rr >= 64) { M1 = rmax; C1 = bc; }
        else          { M0 = rmax; C0 = bc; }
      }
    }
  }
}

__global__ void k_wcvt(const float* __restrict__ wqkv, const float* __restrict__ wout,
                       unsigned short* __restrict__ wqkv_bf, unsigned short* __restrict__ wout_bf) {
  int i = blockIdx.x * 256 + threadIdx.x;
  if (i < 196608) wqkv_bf[i] = f2bf(wqkv[i]);
  int j = i - 196608;
  if (j >= 0 && j < 65536) wout_bf[j] = f2bf(wout[j]);
}

__global__ void k_toks(const float* __restrict__ x, const int* __restrict__ keep,
                       unsigned short* __restrict__ tokbf) {
  int w = blockIdx.x;
  int b = w / NKEEP;
  int sy = keep[w * 2 + 0], sx = keep[w * 2 + 1];
  int tid = threadIdx.x;
  int ch = tid & 127, th = tid >> 7;
  const float* xb = x + (size_t)b * 65536 * DIM;
  for (int it = 0; it < 128; ++it) {
    int tk = it * 2 + th;
    int i = tk >> 4, j = tk & 15;
    float offy = (i + 0.5f) * 0.9375f;
    float offx = (j + 0.5f) * 0.9375f;
    int li = (int)offy, lj = (int)offx;
    float fy = offy - (float)li, fx = offx - (float)lj;
    const float* p = xb + ((size_t)((sy + li) * HWD + (sx + lj))) * DIM + ch;
    float v00 = p[0], v01 = p[DIM], v10 = p[HWD * DIM], v11 = p[HWD * DIM + DIM];
    float w00 = (1.f - fy) * (1.f - fx), w01 = (1.f - fy) * fx;
    float w10 = fy * (1.f - fx), w11 = fy * fx;
    tokbf[((size_t)w * NTOK + tk) * DIM + ch] = f2bf(w00 * v00 + w01 * v01 + w10 * v10 + w11 * v11);
  }
}

/* ===== Candidate: q-split fused attention, register-dieted and compiled
   at launch_bounds(512,4) so the compiler targets <=128 VGPR (2 blocks/CU
   with 50.5 KB LDS). All MFMA fragment loads are half-chunked so at most
   16 fragment VGPRs are live at once (R12 lesson: un-chunked ka[4][2]/aw[8]
   pushed the (512,2) build past 128). Per-output accumulation order is
   unchanged -> bit-identical to the R11-validated k_attn3. Launcher uses
   it only if numRegs<=128 && no scratch; else proven R8 k_attn. ===== */
__global__ __launch_bounds__(512, 4) void k_attn3(
    const unsigned short* __restrict__ tokbf,
    const unsigned short* __restrict__ wqkv,
    const unsigned short* __restrict__ wout,
    unsigned short* __restrict__ po) {
  __shared__ __align__(16) char smem[51712];
  unsigned short* Kh  = (unsigned short*)smem;               /* [128][KP3] */
  unsigned short* VTh = (unsigned short*)(smem + 17408);     /* [64][VP3] */
  const int tid = threadIdx.x;
  const int wv = tid >> 6, ln = tid & 63, lo = ln & 15, hi = ln >> 4;
  const int bid = blockIdx.x;
  const int win = bid >> 1, qh = bid & 1;
  unsigned short* QP = (unsigned short*)(smem + 34304 + wv * 2176);  /* [16][KP3] */
  const unsigned short* tw = tokbf + (size_t)win * NTOK * DIM;
  const int qb = qh * 128 + wv * 16;

  f32x4 pacc[8];
#pragma unroll
  for (int mf = 0; mf < 8; ++mf) pacc[mf] = (f32x4){0.f,0.f,0.f,0.f};

  for (int h = 0; h < HEADS; ++h) {
    /* Q stage (wave-private QP) */
    {
      f32x4 qacc[4];
#pragma unroll
      for (int mf = 0; mf < 4; ++mf) qacc[mf] = (f32x4){0.f,0.f,0.f,0.f};
#pragma unroll
      for (int kf = 0; kf < 4; ++kf) {
        short8 bt = ld8_g(&tw[(qb + lo) * 128 + kf * 32 + hi * 8]);
#pragma unroll
        for (int mf = 0; mf < 4; ++mf) {
          short8 aw = ld8_g(wqkv + (size_t)(h * 64 + mf * 16 + lo) * 128 + kf * 32 + hi * 8);
          qacc[mf] = __builtin_amdgcn_mfma_f32_16x16x32_bf16(aw, bt, qacc[mf], 0, 0, 0);
        }
      }
#pragma unroll
      for (int mf = 0; mf < 4; ++mf)
        *(short4v*)&QP[lo * KP3 + mf * 16 + hi * 4] = pk4(qacc[mf] * 0.125f);
    }
    short8 Qb[2];
#pragma unroll
    for (int kf = 0; kf < 2; ++kf)
      Qb[kf] = ld8_lds(&QP[lo * KP3 + kf * 32 + hi * 8]);

    f32x4 Ot[4];
#pragma unroll
    for (int mf = 0; mf < 4; ++mf) Ot[mf] = (f32x4){0.f,0.f,0.f,0.f};
    float mrow = -INFINITY, lrow = 0.f;

    for (int half = 0; half < 2; ++half) {
      __syncthreads();            /* all waves done reading Kh/VTh */
      const int kbase = half * 128 + wv * 16;
      /* K stage */
      {
        f32x4 kacc[4];
#pragma unroll
        for (int mf = 0; mf < 4; ++mf) kacc[mf] = (f32x4){0.f,0.f,0.f,0.f};
#pragma unroll
        for (int kf = 0; kf < 4; ++kf) {
          short8 bt = ld8_g(&tw[(kbase + lo) * 128 + kf * 32 + hi * 8]);
#pragma unroll
          for (int mf = 0; mf < 4; ++mf) {
            short8 aw = ld8_g(wqkv + (size_t)(512 + h * 64 + mf * 16 + lo) * 128 + kf * 32 + hi * 8);
            kacc[mf] = __builtin_amdgcn_mfma_f32_16x16x32_bf16(aw, bt, kacc[mf], 0, 0, 0);
          }
        }
#pragma unroll
        for (int mf = 0; mf < 4; ++mf)
          *(short4v*)&Kh[(wv * 16 + lo) * KP3 + mf * 16 + hi * 4] = pk4(kacc[mf]);
      }
      /* V stage */
      {
        f32x4 vacc[4];
#pragma unroll
        for (int nf = 0; nf < 4; ++nf) vacc[nf] = (f32x4){0.f,0.f,0.f,0.f};
#pragma unroll
        for (int kf = 0; kf < 4; ++kf) {
          short8 at = ld8_g(&tw[(kbase + lo) * 128 + kf * 32 + hi * 8]);
#pragma unroll
          for (int nf = 0; nf < 4; ++nf) {
            short8 bw = ld8_g(wqkv + (size_t)(1024 + h * 64 + nf * 16 + lo) * 128 + kf * 32 + hi * 8);
            vacc[nf] = __builtin_amdgcn_mfma_f32_16x16x32_bf16(at, bw, vacc[nf], 0, 0, 0);
          }
        }
#pragma unroll
        for (int nf = 0; nf < 4; ++nf)
          *(short4v*)&VTh[(nf * 16 + lo) * VP3 + wv * 16 + hi * 4] = pk4(vacc[nf]);
      }
      __syncthreads();            /* Kh/VTh visible */

      for (int ck = 0; ck < 2; ++ck) {
        f32x4 sacc[4];
#pragma unroll
        for (int mf = 0; mf < 4; ++mf) sacc[mf] = (f32x4){0.f,0.f,0.f,0.f};
        /* S = K·Q^T, ka half-chunked (16 frag VGPRs live, not 32) */
#pragma unroll
        for (int kf = 0; kf < 2; ++kf) {
          short8 ka[4];
#pragma unroll
          for (int mf = 0; mf < 4; ++mf)
            ka[mf] = ld8_lds(&Kh[(ck * 64 + mf * 16 + lo) * KP3 + kf * 32 + hi * 8]);
#pragma unroll
          for (int mf = 0; mf < 4; ++mf)
            sacc[mf] = __builtin_amdgcn_mfma_f32_16x16x32_bf16(ka[mf], Qb[kf], sacc[mf], 0, 0, 0);
        }

        float cmax = -INFINITY;
#pragma unroll
        for (int mf = 0; mf < 4; ++mf)
#pragma unroll
          for (int r = 0; r < 4; ++r) cmax = fmaxf(cmax, sacc[mf][r]);
        cmax = fmaxf(cmax, __shfl_xor(cmax, 16));
        cmax = fmaxf(cmax, __shfl_xor(cmax, 32));
        float mnew = fmaxf(mrow, cmax);
        float corr = __expf(mrow - mnew);
        float ps = 0.f;
#pragma unroll
        for (int mf = 0; mf < 4; ++mf)
#pragma unroll
          for (int r = 0; r < 4; ++r) {
            float e = __expf(sacc[mf][r] - mnew);
            sacc[mf][r] = e; ps += e;
          }
        ps += __shfl_xor(ps, 16);
        ps += __shfl_xor(ps, 32);
        lrow = lrow * corr + ps;
        mrow = mnew;
#pragma unroll
        for (int mf = 0; mf < 4; ++mf) Ot[mf] *= corr;

#pragma unroll
        for (int mf = 0; mf < 4; ++mf)
          *(short4v*)&QP[lo * KP3 + mf * 16 + hi * 4] = pk4(sacc[mf]);
        short8 pb[2];
#pragma unroll
        for (int kf = 0; kf < 2; ++kf)
          pb[kf] = ld8_lds(&QP[lo * KP3 + kf * 32 + hi * 8]);
        /* PV, va half-chunked */
#pragma unroll
        for (int kf = 0; kf < 2; ++kf) {
          short8 va[4];
#pragma unroll
          for (int mf = 0; mf < 4; ++mf)
            va[mf] = ld8_lds(&VTh[(mf * 16 + lo) * VP3 + ck * 64 + kf * 32 + hi * 8]);
#pragma unroll
          for (int mf = 0; mf < 4; ++mf)
            Ot[mf] = __builtin_amdgcn_mfma_f32_16x16x32_bf16(va[mf], pb[kf], Ot[mf], 0, 0, 0);
        }
      }
    }

    /* O finalize -> QP, proj accumulate (aw quarter-chunked) */
    {
      float inv = 1.f / lrow;
#pragma unroll
      for (int mf = 0; mf < 4; ++mf)
        *(short4v*)&QP[lo * KP3 + mf * 16 + hi * 4] = pk4(Ot[mf] * inv);
    }
    short8 Ob[2];
#pragma unroll
    for (int kf = 0; kf < 2; ++kf)
      Ob[kf] = ld8_lds(&QP[lo * KP3 + kf * 32 + hi * 8]);
#pragma unroll
    for (int kf = 0; kf < 2; ++kf) {
#pragma unroll
      for (int mh = 0; mh < 2; ++mh) {
        short8 aw[4];
#pragma unroll
        for (int m4 = 0; m4 < 4; ++m4)
          aw[m4] = ld8_g(wout + (size_t)((mh * 4 + m4) * 16 + lo) * 512 + h * 64 + kf * 32 + hi * 8);
#pragma unroll
        for (int m4 = 0; m4 < 4; ++m4)
          pacc[mh * 4 + m4] = __builtin_amdgcn_mfma_f32_16x16x32_bf16(aw[m4], Ob[kf], pacc[mh * 4 + m4], 0, 0, 0);
      }
    }
  }

#pragma unroll
  for (int mf = 0; mf < 8; ++mf)
    *(short4v*)&po[((size_t)win * NTOK + qb + lo) * 128 + mf * 16 + hi * 4] = pk4(pacc[mf]);
}

/* ===== Fallback: proven R8 fused k_attn (182 us, bit-proven) ===== */
__global__ __launch_bounds__(512, 2) void k_attn(
    const unsigned short* __restrict__ tokbf,
    const unsigned short* __restrict__ wqkv,
    const unsigned short* __restrict__ wout,
    unsigned short* __restrict__ po) {
  __shared__ __align__(16) char smem[112128];
  unsigned short* Klds = (unsigned short*)smem;
  unsigned short* VT   = (unsigned short*)(smem + 38912);
  const int tid = threadIdx.x;
  const int wv = tid >> 6, ln = tid & 63;
  const int lo = ln & 15, hi = ln >> 4;
  const int win = blockIdx.x;
  unsigned short* QP = (unsigned short*)(smem + 73216 + wv * 4864);
  const unsigned short* tw = tokbf + (size_t)win * NTOK * DIM;
  const int qrow = wv * 32;

  f32x4 pacc[8][2];
#pragma unroll
  for (int mf = 0; mf < 8; ++mf)
#pragma unroll
    for (int nf = 0; nf < 2; ++nf) pacc[mf][nf] = (f32x4){0.f,0.f,0.f,0.f};

  for (int h = 0; h < HEADS; ++h) {
    if (h) __syncthreads();
    {
      f32x4 kacc[4][2];
#pragma unroll
      for (int mf = 0; mf < 4; ++mf)
#pragma unroll
        for (int nf = 0; nf < 2; ++nf) kacc[mf][nf] = (f32x4){0.f,0.f,0.f,0.f};
#pragma unroll
      for (int kf = 0; kf < 4; ++kf) {
        short8 aw[4], bt[2];
#pragma unroll
        for (int mf = 0; mf < 4; ++mf)
          aw[mf] = ld8_g(wqkv + (size_t)(512 + h * 64 + mf * 16 + lo) * 128 + kf * 32 + hi * 8);
#pragma unroll
        for (int nf = 0; nf < 2; ++nf)
          bt[nf] = ld8_g(&tw[(qrow + nf * 16 + lo) * 128 + kf * 32 + hi * 8]);
#pragma unroll
        for (int mf = 0; mf < 4; ++mf)
#pragma unroll
          for (int nf = 0; nf < 2; ++nf)
            kacc[mf][nf] = __builtin_amdgcn_mfma_f32_16x16x32_bf16(aw[mf], bt[nf], kacc[mf][nf], 0, 0, 0);
      }
#pragma unroll
      for (int mf = 0; mf < 4; ++mf)
#pragma unroll
        for (int nf = 0; nf < 2; ++nf)
          *(short4v*)&Klds[(qrow + nf * 16 + lo) * KPAD + mf * 16 + hi * 4] = pk4(kacc[mf][nf]);
    }
    {
      f32x4 vacc[2][4];
#pragma unroll
      for (int mf = 0; mf < 2; ++mf)
#pragma unroll
        for (int nf = 0; nf < 4; ++nf) vacc[mf][nf] = (f32x4){0.f,0.f,0.f,0.f};
#pragma unroll
      for (int kf = 0; kf < 4; ++kf) {
        short8 at[2], bw[4];
#pragma unroll
        for (int mf = 0; mf < 2; ++mf)
          at[mf] = ld8_g(&tw[(qrow + mf * 16 + lo) * 128 + kf * 32 + hi * 8]);
#pragma unroll
        for (int nf = 0; nf < 4; ++nf)
          bw[nf] = ld8_g(wqkv + (size_t)(1024 + h * 64 + nf * 16 + lo) * 128 + kf * 32 + hi * 8);
#pragma unroll
        for (int mf = 0; mf < 2; ++mf)
#pragma unroll
          for (int nf = 0; nf < 4; ++nf)
            vacc[mf][nf] = __builtin_amdgcn_mfma_f32_16x16x32_bf16(at[mf], bw[nf], vacc[mf][nf], 0, 0, 0);
      }
#pragma unroll
      for (int mf = 0; mf < 2; ++mf)
#pragma unroll
        for (int nf = 0; nf < 4; ++nf)
          *(short4v*)&VT[(nf * 16 + lo) * VPAD + qrow + mf * 16 + hi * 4] = pk4(vacc[mf][nf]);
    }
    {
      f32x4 qacc[4][2];
#pragma unroll
      for (int mf = 0; mf < 4; ++mf)
#pragma unroll
        for (int nf = 0; nf < 2; ++nf) qacc[mf][nf] = (f32x4){0.f,0.f,0.f,0.f};
#pragma unroll
      for (int kf = 0; kf < 4; ++kf) {
        short8 aw[4], bt[2];
#pragma unroll
        for (int mf = 0; mf < 4; ++mf)
          aw[mf] = ld8_g(wqkv + (size_t)(h * 64 + mf * 16 + lo) * 128 + kf * 32 + hi * 8);
#pragma unroll
        for (int nf = 0; nf < 2; ++nf)
          bt[nf] = ld8_g(&tw[(qrow + nf * 16 + lo) * 128 + kf * 32 + hi * 8]);
#pragma unroll
        for (int mf = 0; mf < 4; ++mf)
#pragma unroll
          for (int nf = 0; nf < 2; ++nf)
            qacc[mf][nf] = __builtin_amdgcn_mfma_f32_16x16x32_bf16(aw[mf], bt[nf], qacc[mf][nf], 0, 0, 0);
      }
#pragma unroll
      for (int mf = 0; mf < 4; ++mf)
#pragma unroll
        for (int nf = 0; nf < 2; ++nf)
          *(short4v*)&QP[(nf * 16 + lo) * KPAD + mf * 16 + hi * 4] = pk4(qacc[mf][nf] * 0.125f);
    }
    __syncthreads();

    short8 Qb[2][2];
#pragma unroll
    for (int nf = 0; nf < 2; ++nf)
#pragma unroll
      for (int kf = 0; kf < 2; ++kf)
        Qb[nf][kf] = ld8_lds(&QP[(nf * 16 + lo) * KPAD + kf * 32 + hi * 8]);

    f32x4 Ot[4][2];
#pragma unroll
    for (int mf = 0; mf < 4; ++mf)
#pragma unroll
      for (int nf = 0; nf < 2; ++nf) Ot[mf][nf] = (f32x4){0.f,0.f,0.f,0.f};
    float mrow[2] = {-INFINITY, -INFINITY};
    float lrow[2] = {0.f, 0.f};

    for (int ck = 0; ck < 4; ++ck) {
      f32x4 sacc[4][2];
#pragma unroll
      for (int mf = 0; mf < 4; ++mf)
#pragma unroll
        for (int nf = 0; nf < 2; ++nf) sacc[mf][nf] = (f32x4){0.f,0.f,0.f,0.f};
      short8 ka[4][2];
#pragma unroll
      for (int mf = 0; mf < 4; ++mf)
#pragma unroll
        for (int kf = 0; kf < 2; ++kf)
          ka[mf][kf] = ld8_lds(&Klds[(ck * 64 + mf * 16 + lo) * KPAD + kf * 32 + hi * 8]);
#pragma unroll
      for (int mf = 0; mf < 4; ++mf)
#pragma unroll
        for (int nf = 0; nf < 2; ++nf)
#pragma unroll
          for (int kf = 0; kf < 2; ++kf)
            sacc[mf][nf] = __builtin_amdgcn_mfma_f32_16x16x32_bf16(ka[mf][kf], Qb[nf][kf], sacc[mf][nf], 0, 0, 0);

#pragma unroll
      for (int nf = 0; nf < 2; ++nf) {
        float cmax = -INFINITY;
#pragma unroll
        for (int mf = 0; mf < 4; ++mf)
#pragma unroll
          for (int r = 0; r < 4; ++r) cmax = fmaxf(cmax, sacc[mf][nf][r]);
        cmax = fmaxf(cmax, __shfl_xor(cmax, 16));
        cmax = fmaxf(cmax, __shfl_xor(cmax, 32));
        float mnew = fmaxf(mrow[nf], cmax);
        float corr = __expf(mrow[nf] - mnew);
        float ps = 0.f;
#pragma unroll
        for (int mf = 0; mf < 4; ++mf)
#pragma unroll
          for (int r = 0; r < 4; ++r) {
            float e = __expf(sacc[mf][nf][r] - mnew);
            sacc[mf][nf][r] = e; ps += e;
          }
        ps += __shfl_xor(ps, 16);
        ps += __shfl_xor(ps, 32);
        lrow[nf] = lrow[nf] * corr + ps;
        mrow[nf] = mnew;
#pragma unroll
        for (int mf = 0; mf < 4; ++mf) Ot[mf][nf] *= corr;
      }
#pragma unroll
      for (int mf = 0; mf < 4; ++mf)
#pragma unroll
        for (int nf = 0; nf < 2; ++nf)
          *(short4v*)&QP[(nf * 16 + lo) * KPAD + mf * 16 + hi * 4] = pk4(sacc[mf][nf]);
      short8 pb[2][2], va[4][2];
#pragma unroll
      for (int nf = 0; nf < 2; ++nf)
#pragma unroll
        for (int kf = 0; kf < 2; ++kf)
          pb[nf][kf] = ld8_lds(&QP[(nf * 16 + lo) * KPAD + kf * 32 + hi * 8]);
#pragma unroll
      for (int mf = 0; mf < 4; ++mf)
#pragma unroll
        for (int kf = 0; kf < 2; ++kf)
          va[mf][kf] = ld8_lds(&VT[(mf * 16 + lo) * VPAD + ck * 64 + kf * 32 + hi * 8]);
#pragma unroll
      for (int mf = 0; mf < 4; ++mf)
#pragma unroll
        for (int nf = 0; nf < 2; ++nf)
#pragma unroll
          for (int kf = 0; kf < 2; ++kf)
            Ot[mf][nf] = __builtin_amdgcn_mfma_f32_16x16x32_bf16(va[mf][kf], pb[nf][kf], Ot[mf][nf], 0, 0, 0);
    }

#pragma unroll
    for (int nf = 0; nf < 2; ++nf) {
      float inv = 1.f / lrow[nf];
#pragma unroll
      for (int mf = 0; mf < 4; ++mf)
        *(short4v*)&QP[(nf * 16 + lo) * KPAD + mf * 16 + hi * 4] = pk4(Ot[mf][nf] * inv);
    }
    short8 Ob[2][2];
#pragma unroll
    for (int nf = 0; nf < 2; ++nf)
#pragma unroll
      for (int kf = 0; kf < 2; ++kf)
        Ob[nf][kf] = ld8_lds(&QP[(nf * 16 + lo) * KPAD + kf * 32 + hi * 8]);
#pragma unroll
    for (int kf = 0; kf < 2; ++kf) {
      short8 aw[8];
#pragma unroll
      for (int mf = 0; mf < 8; ++mf)
        aw[mf] = ld8_g(wout + (size_t)(mf * 16 + lo) * 512 + h * 64 + kf * 32 + hi * 8);
#pragma unroll
      for (int mf = 0; mf < 8; ++mf)
#pragma unroll
        for (int nf = 0; nf < 2; ++nf)
          pacc[mf][nf] = __builtin_amdgcn_mfma_f32_16x16x32_bf16(aw[mf], Ob[nf][kf], pacc[mf][nf], 0, 0, 0);
    }
  }
#pragma unroll
  for (int mf = 0; mf < 8; ++mf)
#pragma unroll
    for (int nf = 0; nf < 2; ++nf)
      *(short4v*)&po[((size_t)win * NTOK + qrow + nf * 16 + lo) * 128 + mf * 16 + hi * 4] = pk4(pacc[mf][nf]);
}

/* Gather finalize (proven). */
__global__ void k_final(const float* __restrict__ x, const unsigned short* __restrict__ po,
                        const int* __restrict__ keep, const float* __restrict__ bout,
                        float* __restrict__ out) {
  __shared__ int kp[2 * NKEEP];
  int tid = threadIdx.x;
  int gid = blockIdx.x * 256 + tid;
  int chq = gid & 3, pix = gid >> 2;
  int b = pix >> 16, pb = pix & 65535, y = pb >> 8, xx = pb & 255;
  if (tid < 2 * NKEEP) kp[tid] = keep[b * 2 * NKEEP + tid];
  __syncthreads();
  float acc[32];
#pragma unroll
  for (int i = 0; i < 32; ++i) acc[i] = 0.f;
  float cnt = 0.f;
  for (int w = 0; w < NKEEP; ++w) {
    int dy = y - kp[2 * w], dx = xx - kp[2 * w + 1];
    if ((unsigned)dy < 16u && (unsigned)dx < 16u) {
      cnt += 1.f;
      const unsigned short* pp = po + ((size_t)(b * NKEEP + w) * NTOK + dy * 16 + dx) * 128 + chq * 32;
#pragma unroll
      for (int k2 = 0; k2 < 4; ++k2) {
        short8 v = ld8_g(pp + k2 * 8);
#pragma unroll
        for (int j = 0; j < 8; ++j) {
          union { unsigned u; float f; } cv;
          cv.u = ((unsigned)(unsigned short)v[j]) << 16;
          acc[k2 * 8 + j] += cv.f;
        }
      }
    }
  }
  size_t base = (size_t)pix * 128 + chq * 32;
  float inv = 1.f / (cnt + 1e-10f);
#pragma unroll
  for (int i = 0; i < 32; ++i)
    out[base + i] = x[base + i] + (acc[i] + cnt * bout[chq * 32 + i]) * inv;
}

extern "C" void kernel_launch(void* const* d_in, const int* in_sizes, int n_in,
                              void* d_out, int out_size, void* d_ws, size_t ws_size,
                              hipStream_t stream) {
  const float* x    = (const float*)d_in[0];
  const float* prob = (const float*)d_in[1];
  const float* fixw = (const float*)d_in[2];
  const float* wqkv = (const float*)d_in[3];
  const float* wout = (const float*)d_in[4];
  const float* bout = (const float*)d_in[5];
  float* out = (float*)d_out;
  float* ws  = (float*)d_ws;
  if (ws_size < (size_t)WS_FLOATS * 4) return;  /* need >= 27.3 MB */

  float* ent  = ws + OFF_ENT;
  float* scp  = ws + OFF_SCORE;
  int*   keep = (int*)(ws + OFF_KEEP);
  unsigned short* wqkv_bf = (unsigned short*)(ws + OFF_WQKV);
  unsigned short* wout_bf = (unsigned short*)(ws + OFF_WOUT);
  unsigned short* tokbf   = (unsigned short*)(ws + OFF_TOKBF);
  unsigned short* po      = (unsigned short*)(ws + OFF_PO);

  /* Deterministic host-side check: use the q-split kernel only if the
     compiler kept it spill-free within 2-blocks/CU residency. */
  hipFuncAttributes fa;
  int use3 = 0;
  if (hipFuncGetAttributes(&fa, (const void*)k_attn3) == hipSuccess)
    use3 = (fa.numRegs > 0 && fa.numRegs <= 128 && fa.localSizeBytes == 0);

  k_entropy<<<256, 256, 0, stream>>>(prob, ent);
  k_score<<<(NB * SCPAD + 255) / 256, 256, 0, stream>>>(ent, fixw, scp);
  k_wcvt<<<1024, 256, 0, stream>>>(wqkv, wout, wqkv_bf, wout_bf);
  k_nms<<<NB, 64, 0, stream>>>(scp, keep);
  k_toks<<<NWTOT, 256, 0, stream>>>(x, keep, tokbf);
  if (use3)
    k_attn3<<<NWTOT * 2, 512, 0, stream>>>(tokbf, wqkv_bf, wout_bf, po);
  else
    k_attn<<<NWTOT, 512, 0, stream>>>(tokbf, wqkv_bf, wout_bf, po);
  k_final<<<NB * 65536 * 4 / 256, 256, 0, stream>>>(x, po, keep, bout, out);
}

// Round 14
// 390.080 us; speedup vs baseline: 2.0532x; 1.0016x over previous
//
#include <hip/hip_runtime.h>
#include <math.h>

#define NB 4
#define NWIN 121
#define NBOX (NWIN*NWIN)   /* 14641 */
#define NKEEP 50
#define HWD 256
#define DIM 128
#define HEADS 8
#define NTOK 256
#define NWTOT (NB*NKEEP)   /* 200 */
#define SCPAD 15616        /* 122 rows x 128 cols, swizzled, per batch */

/* ws layout (float units) — proven R8 layout */
#define OFF_ENT   0          /* 65536 */
#define OFF_SCORE 65536      /* NB*SCPAD = 62464 */
#define OFF_KEEP  128128     /* 100 floats */
#define OFF_WQKV  128256     /* 98304 f */
#define OFF_WOUT  226560     /* 32768 f */
#define OFF_TOKBF 259328     /* 3276800 f */
#define OFF_PO    3536128    /* 3276800 f */
#define WS_FLOATS 6812928    /* 27.3 MB — proven */

#define KPAD 76              /* R8 fused-kernel strides */
#define VPAD 268
#define KP3 68               /* k_attn3 strides */
#define VP3 132

typedef __attribute__((ext_vector_type(8))) short short8;
typedef __attribute__((ext_vector_type(4))) short short4v;
typedef __attribute__((ext_vector_type(4))) float f32x4;

static __device__ __forceinline__ unsigned short f2bf(float f) {
  union { float f; unsigned u; } v; v.f = f;
  unsigned r = (v.u + 0x7fffu + ((v.u >> 16) & 1u)) >> 16;
  return (unsigned short)r;
}
static __device__ __forceinline__ short4v pk4(f32x4 a) {
  short4v r;
  r[0] = (short)f2bf(a[0]); r[1] = (short)f2bf(a[1]);
  r[2] = (short)f2bf(a[2]); r[3] = (short)f2bf(a[3]);
  return r;
}
static __device__ __forceinline__ short8 ld8_lds(const unsigned short* p) {
  short4v a = *(const short4v*)p;
  short4v b = *(const short4v*)(p + 4);
  short8 r;
  r[0]=a[0]; r[1]=a[1]; r[2]=a[2]; r[3]=a[3];
  r[4]=b[0]; r[5]=b[1]; r[6]=b[2]; r[7]=b[3];
  return r;
}
static __device__ __forceinline__ short8 ld8_g(const unsigned short* p) {
  return *(const short8*)p;   /* 16B-aligned global */
}

template<int CTRL>
static __device__ __forceinline__ float dppmax(float v) {
  union { float f; int i; } a, r; a.f = v;
  r.i = __builtin_amdgcn_update_dpp(a.i, a.i, CTRL, 0xf, 0xf, false);
  return fmaxf(v, r.f);
}
static __device__ __forceinline__ float wavemax(float v) {
  v = dppmax<0x111>(v); v = dppmax<0x112>(v);
  v = dppmax<0x114>(v); v = dppmax<0x118>(v);
  v = dppmax<0x142>(v); v = dppmax<0x143>(v);
  union { float f; int i; } gi, gm; gi.f = v;
  gm.i = __builtin_amdgcn_readlane(gi.i, 63);
  return gm.f;
}

__global__ void k_entropy(const float* __restrict__ prob, float* __restrict__ ent) {
  int idx = blockIdx.x * 256 + threadIdx.x;
  int b = idx >> 14, p = idx & 16383;
  float p0 = prob[(size_t)(b * 2) * 16384 + p];
  float p1 = prob[(size_t)(b * 2 + 1) * 16384 + p];
  ent[idx] = -(p0 * log2f(p0 + 1e-10f) + p1 * log2f(p1 + 1e-10f));
}

__global__ void k_score(const float* __restrict__ ent, const float* __restrict__ fw,
                        float* __restrict__ scp) {
  int gid = blockIdx.x * 256 + threadIdx.x;
  if (gid >= NB * SCPAD) return;
  int b = gid / SCPAD, idx = gid % SCPAD;
  int r = idx >> 7, c = idx & 127;
  float s = -INFINITY;
  if (r < NWIN && c < NWIN) {
    const float* e = ent + b * 16384 + r * 128 + c;
    float a = 0.f;
#pragma unroll
    for (int rr = 0; rr < 8; ++rr)
#pragma unroll
      for (int cc = 0; cc < 8; ++cc)
        a += e[rr * 128 + cc] * fw[rr * 8 + cc];
    s = a * (1.0f / 64.0f);
  }
  scp[b * SCPAD + (r << 7) + (c ^ ((r & 7) << 2))] = s;
}

/* Single-wave NMS v4 (proven R8). */
__global__ void k_nms(const float* __restrict__ scp, int* __restrict__ keep) {
  __shared__ float sc[SCPAD];
  int b = blockIdx.x, l = threadIdx.x;
  const float* src = scp + b * SCPAD;
  for (int cb = 0; cb < 64; cb += 8) {
    f32x4 t[8];
#pragma unroll
    for (int i = 0; i < 8; ++i) {
      int idx = (cb + i) * 256 + l * 4;
      if (idx < SCPAD) t[i] = *(const f32x4*)&src[idx];
    }
#pragma unroll
    for (int i = 0; i < 8; ++i) {
      int idx = (cb + i) * 256 + l * 4;
      if (idx < SCPAD) *(f32x4*)&sc[idx] = t[i];
    }
  }
  float M0 = -INFINITY, M1 = -INFINITY; int C0 = 0, C1 = 0;
#pragma unroll
  for (int slot = 0; slot < 2; ++slot) {
    int r = l + slot * 64;
    if (slot == 1 && r >= NWIN) break;
    int r7 = (r & 7) << 2, rbase = r << 7;
    float bv0=-INFINITY,bv1=-INFINITY,bv2=-INFINITY,bv3=-INFINITY;
    int bc0=0,bc1=0,bc2=0,bc3=0;
    for (int lb = 0; lb < 32; ++lb) {
      f32x4 v = *(const f32x4*)&sc[rbase + ((lb << 2) ^ r7)];
      int c0 = lb << 2;
      if (v[0] > bv0) { bv0 = v[0]; bc0 = c0; }
      if (v[1] > bv1) { bv1 = v[1]; bc1 = c0 + 1; }
      if (v[2] > bv2) { bv2 = v[2]; bc2 = c0 + 2; }
      if (v[3] > bv3) { bv3 = v[3]; bc3 = c0 + 3; }
    }
    float bv = bv0; int bc = bc0;
    if (bv1 > bv || (bv1 == bv && bc1 < bc)) { bv = bv1; bc = bc1; }
    if (bv2 > bv || (bv2 == bv && bc2 < bc)) { bv = bv2; bc = bc2; }
    if (bv3 > bv || (bv3 == bv && bc3 < bc)) { bv = bv3; bc = bc3; }
    if (slot == 0) { M0 = bv; C0 = bc; } else { M1 = bv; C1 = bc; }
  }
  for (int k = 0; k < NKEEP; ++k) {
    float gmax = wavemax(fmaxf(M0, M1));
    unsigned long long b0 = __ballot(M0 == gmax);
    unsigned long long b1 = __ballot(M1 == gmax);
    int R;
    if (b0) R = __ffsll((unsigned long long)b0) - 1;
    else    R = 64 + __ffsll((unsigned long long)b1) - 1;
    int Cc = (R < 64) ? __builtin_amdgcn_readlane(C0, R)
                      : __builtin_amdgcn_readlane(C1, R - 64);
    if (l == 0) {
      keep[(b * NKEEP + k) * 2 + 0] = 2 * R;
      keep[(b * NKEEP + k) * 2 + 1] = 2 * Cc;
    }
    bool kill0 = false, kill1 = false;
    {
      int dy = l - R, ady = dy < 0 ? -dy : dy;
      if (ady <= 4) {
        int ih = 15 - 2 * ady;
#pragma unroll
        for (int dx = -4; dx <= 4; ++dx) {
          int adx = dx < 0 ? -dx : dx;
          if ((15 - 2 * adx) * ih > 75) {
            int cc = Cc + dx;
            if ((unsigned)cc < (unsigned)NWIN)
              sc[(l << 7) + (cc ^ ((l & 7) << 2))] = -INFINITY;
          }
        }
        int adx = C0 - Cc; adx = adx < 0 ? -adx : adx;
        kill0 = (adx <= 4) && ((15 - 2 * adx) * ih > 75);
      }
    }
    if (l + 64 < NWIN) {
      int r1 = l + 64;
      int dy = r1 - R, ady = dy < 0 ? -dy : dy;
      if (ady <= 4) {
        int ih = 15 - 2 * ady;
#pragma unroll
        for (int dx = -4; dx <= 4; ++dx) {
          int adx = dx < 0 ? -dx : dx;
          if ((15 - 2 * adx) * ih > 75) {
            int cc = Cc + dx;
            if ((unsigned)cc < (unsigned)NWIN)
              sc[(r1 << 7) + (cc ^ ((r1 & 7) << 2))] = -INFINITY;
          }
        }
        int adx = C1 - Cc; adx = adx < 0 ? -adx : adx;
        kill1 = (adx <= 4) && ((15 - 2 * adx) * ih > 75);
      }
    }
    unsigned long long need0 = __ballot(kill0);
    unsigned long long need1 = __ballot(kill1);
    while (need0 | need1) {
      int rr;
      if (need0) { rr = __ffsll((unsigned long long)need0) - 1; need0 &= need0 - 1; }
      else       { rr = __ffsll((unsigned long long)need1) - 1 + 64; need1 &= need1 - 1; }
      int r7 = (rr & 7) << 2, rbase = rr << 7;
      float v0 = sc[rbase + (l ^ r7)];
      float v1 = sc[rbase + ((l + 64) ^ r7)];
      float rmax = wavemax(fmaxf(v0, v1));
      unsigned long long e0 = __ballot(v0 == rmax);
      unsigned long long e1 = __ballot(v1 == rmax);
      int bc;
      if (e0) bc = __ffsll((unsigned long long)e0) - 1;
      else    bc = 64 + __ffsll((unsigned long long)e1) - 1;
      if (l == (rr & 63)) {
        if (rr >= 64) { M1 = rmax; C1 = bc; }
        else          { M0 = rmax; C0 = bc; }
      }
    }
  }
}

__global__ void k_wcvt(const float* __restrict__ wqkv, const float* __restrict__ wout,
                       unsigned short* __restrict__ wqkv_bf, unsigned short* __restrict__ wout_bf) {
  int i = blockIdx.x * 256 + threadIdx.x;
  if (i < 196608) wqkv_bf[i] = f2bf(wqkv[i]);
  int j = i - 196608;
  if (j >= 0 && j < 65536) wout_bf[j] = f2bf(wout[j]);
}

__global__ void k_toks(const float* __restrict__ x, const int* __restrict__ keep,
                       unsigned short* __restrict__ tokbf) {
  int w = blockIdx.x;
  int b = w / NKEEP;
  int sy = keep[w * 2 + 0], sx = keep[w * 2 + 1];
  int tid = threadIdx.x;
  int ch = tid & 127, th = tid >> 7;
  const float* xb = x + (size_t)b * 65536 * DIM;
  for (int it = 0; it < 128; ++it) {
    int tk = it * 2 + th;
    int i = tk >> 4, j = tk & 15;
    float offy = (i + 0.5f) * 0.9375f;
    float offx = (j + 0.5f) * 0.9375f;
    int li = (int)offy, lj = (int)offx;
    float fy = offy - (float)li, fx = offx - (float)lj;
    const float* p = xb + ((size_t)((sy + li) * HWD + (sx + lj))) * DIM + ch;
    float v00 = p[0], v01 = p[DIM], v10 = p[HWD * DIM], v11 = p[HWD * DIM + DIM];
    float w00 = (1.f - fy) * (1.f - fx), w01 = (1.f - fy) * fx;
    float w10 = fy * (1.f - fx), w11 = fy * fx;
    tokbf[((size_t)w * NTOK + tk) * DIM + ch] = f2bf(w00 * v00 + w01 * v01 + w10 * v10 + w11 * v11);
  }
}

/* ===== Candidate: q-split fused attention. Register-dieted (half-chunked
   MFMA fragment loads, <=16 frag VGPRs live) AND compiled at
   launch_bounds(512,2) -> VGPR cap 128 (R13 lesson: (512,4) caps at 64 and
   force-spills; (512,2) caps at 128 = exactly what the diet targets).
   LDS 50.5 KB + <=128 VGPR -> 2 blocks/CU residency for the 400-block grid.
   Accumulation order per output unchanged -> bit-identical to R11's
   validated k_attn3. Launcher uses it only if numRegs<=128 && no scratch. */
__global__ __launch_bounds__(512, 2) void k_attn3(
    const unsigned short* __restrict__ tokbf,
    const unsigned short* __restrict__ wqkv,
    const unsigned short* __restrict__ wout,
    unsigned short* __restrict__ po) {
  __shared__ __align__(16) char smem[51712];
  unsigned short* Kh  = (unsigned short*)smem;               /* [128][KP3] */
  unsigned short* VTh = (unsigned short*)(smem + 17408);     /* [64][VP3] */
  const int tid = threadIdx.x;
  const int wv = tid >> 6, ln = tid & 63, lo = ln & 15, hi = ln >> 4;
  const int bid = blockIdx.x;
  const int win = bid >> 1, qh = bid & 1;
  unsigned short* QP = (unsigned short*)(smem + 34304 + wv * 2176);  /* [16][KP3] */
  const unsigned short* tw = tokbf + (size_t)win * NTOK * DIM;
  const int qb = qh * 128 + wv * 16;

  f32x4 pacc[8];
#pragma unroll
  for (int mf = 0; mf < 8; ++mf) pacc[mf] = (f32x4){0.f,0.f,0.f,0.f};

  for (int h = 0; h < HEADS; ++h) {
    /* Q stage (wave-private QP) */
    {
      f32x4 qacc[4];
#pragma unroll
      for (int mf = 0; mf < 4; ++mf) qacc[mf] = (f32x4){0.f,0.f,0.f,0.f};
#pragma unroll
      for (int kf = 0; kf < 4; ++kf) {
        short8 bt = ld8_g(&tw[(qb + lo) * 128 + kf * 32 + hi * 8]);
#pragma unroll
        for (int mf = 0; mf < 4; ++mf) {
          short8 aw = ld8_g(wqkv + (size_t)(h * 64 + mf * 16 + lo) * 128 + kf * 32 + hi * 8);
          qacc[mf] = __builtin_amdgcn_mfma_f32_16x16x32_bf16(aw, bt, qacc[mf], 0, 0, 0);
        }
      }
#pragma unroll
      for (int mf = 0; mf < 4; ++mf)
        *(short4v*)&QP[lo * KP3 + mf * 16 + hi * 4] = pk4(qacc[mf] * 0.125f);
    }
    short8 Qb[2];
#pragma unroll
    for (int kf = 0; kf < 2; ++kf)
      Qb[kf] = ld8_lds(&QP[lo * KP3 + kf * 32 + hi * 8]);

    f32x4 Ot[4];
#pragma unroll
    for (int mf = 0; mf < 4; ++mf) Ot[mf] = (f32x4){0.f,0.f,0.f,0.f};
    float mrow = -INFINITY, lrow = 0.f;

    for (int half = 0; half < 2; ++half) {
      __syncthreads();            /* all waves done reading Kh/VTh */
      const int kbase = half * 128 + wv * 16;
      /* K stage */
      {
        f32x4 kacc[4];
#pragma unroll
        for (int mf = 0; mf < 4; ++mf) kacc[mf] = (f32x4){0.f,0.f,0.f,0.f};
#pragma unroll
        for (int kf = 0; kf < 4; ++kf) {
          short8 bt = ld8_g(&tw[(kbase + lo) * 128 + kf * 32 + hi * 8]);
#pragma unroll
          for (int mf = 0; mf < 4; ++mf) {
            short8 aw = ld8_g(wqkv + (size_t)(512 + h * 64 + mf * 16 + lo) * 128 + kf * 32 + hi * 8);
            kacc[mf] = __builtin_amdgcn_mfma_f32_16x16x32_bf16(aw, bt, kacc[mf], 0, 0, 0);
          }
        }
#pragma unroll
        for (int mf = 0; mf < 4; ++mf)
          *(short4v*)&Kh[(wv * 16 + lo) * KP3 + mf * 16 + hi * 4] = pk4(kacc[mf]);
      }
      /* V stage */
      {
        f32x4 vacc[4];
#pragma unroll
        for (int nf = 0; nf < 4; ++nf) vacc[nf] = (f32x4){0.f,0.f,0.f,0.f};
#pragma unroll
        for (int kf = 0; kf < 4; ++kf) {
          short8 at = ld8_g(&tw[(kbase + lo) * 128 + kf * 32 + hi * 8]);
#pragma unroll
          for (int nf = 0; nf < 4; ++nf) {
            short8 bw = ld8_g(wqkv + (size_t)(1024 + h * 64 + nf * 16 + lo) * 128 + kf * 32 + hi * 8);
            vacc[nf] = __builtin_amdgcn_mfma_f32_16x16x32_bf16(at, bw, vacc[nf], 0, 0, 0);
          }
        }
#pragma unroll
        for (int nf = 0; nf < 4; ++nf)
          *(short4v*)&VTh[(nf * 16 + lo) * VP3 + wv * 16 + hi * 4] = pk4(vacc[nf]);
      }
      __syncthreads();            /* Kh/VTh visible */

      for (int ck = 0; ck < 2; ++ck) {
        f32x4 sacc[4];
#pragma unroll
        for (int mf = 0; mf < 4; ++mf) sacc[mf] = (f32x4){0.f,0.f,0.f,0.f};
        /* S = K·Q^T, ka half-chunked (16 frag VGPRs live) */
#pragma unroll
        for (int kf = 0; kf < 2; ++kf) {
          short8 ka[4];
#pragma unroll
          for (int mf = 0; mf < 4; ++mf)
            ka[mf] = ld8_lds(&Kh[(ck * 64 + mf * 16 + lo) * KP3 + kf * 32 + hi * 8]);
#pragma unroll
          for (int mf = 0; mf < 4; ++mf)
            sacc[mf] = __builtin_amdgcn_mfma_f32_16x16x32_bf16(ka[mf], Qb[kf], sacc[mf], 0, 0, 0);
        }

        float cmax = -INFINITY;
#pragma unroll
        for (int mf = 0; mf < 4; ++mf)
#pragma unroll
          for (int r = 0; r < 4; ++r) cmax = fmaxf(cmax, sacc[mf][r]);
        cmax = fmaxf(cmax, __shfl_xor(cmax, 16));
        cmax = fmaxf(cmax, __shfl_xor(cmax, 32));
        float mnew = fmaxf(mrow, cmax);
        float corr = __expf(mrow - mnew);
        float ps = 0.f;
#pragma unroll
        for (int mf = 0; mf < 4; ++mf)
#pragma unroll
          for (int r = 0; r < 4; ++r) {
            float e = __expf(sacc[mf][r] - mnew);
            sacc[mf][r] = e; ps += e;
          }
        ps += __shfl_xor(ps, 16);
        ps += __shfl_xor(ps, 32);
        lrow = lrow * corr + ps;
        mrow = mnew;
#pragma unroll
        for (int mf = 0; mf < 4; ++mf) Ot[mf] *= corr;

#pragma unroll
        for (int mf = 0; mf < 4; ++mf)
          *(short4v*)&QP[lo * KP3 + mf * 16 + hi * 4] = pk4(sacc[mf]);
        short8 pb[2];
#pragma unroll
        for (int kf = 0; kf < 2; ++kf)
          pb[kf] = ld8_lds(&QP[lo * KP3 + kf * 32 + hi * 8]);
        /* PV, va half-chunked */
#pragma unroll
        for (int kf = 0; kf < 2; ++kf) {
          short8 va[4];
#pragma unroll
          for (int mf = 0; mf < 4; ++mf)
            va[mf] = ld8_lds(&VTh[(mf * 16 + lo) * VP3 + ck * 64 + kf * 32 + hi * 8]);
#pragma unroll
          for (int mf = 0; mf < 4; ++mf)
            Ot[mf] = __builtin_amdgcn_mfma_f32_16x16x32_bf16(va[mf], pb[kf], Ot[mf], 0, 0, 0);
        }
      }
    }

    /* O finalize -> QP, proj accumulate (aw quarter-chunked) */
    {
      float inv = 1.f / lrow;
#pragma unroll
      for (int mf = 0; mf < 4; ++mf)
        *(short4v*)&QP[lo * KP3 + mf * 16 + hi * 4] = pk4(Ot[mf] * inv);
    }
    short8 Ob[2];
#pragma unroll
    for (int kf = 0; kf < 2; ++kf)
      Ob[kf] = ld8_lds(&QP[lo * KP3 + kf * 32 + hi * 8]);
#pragma unroll
    for (int kf = 0; kf < 2; ++kf) {
#pragma unroll
      for (int mh = 0; mh < 2; ++mh) {
        short8 aw[4];
#pragma unroll
        for (int m4 = 0; m4 < 4; ++m4)
          aw[m4] = ld8_g(wout + (size_t)((mh * 4 + m4) * 16 + lo) * 512 + h * 64 + kf * 32 + hi * 8);
#pragma unroll
        for (int m4 = 0; m4 < 4; ++m4)
          pacc[mh * 4 + m4] = __builtin_amdgcn_mfma_f32_16x16x32_bf16(aw[m4], Ob[kf], pacc[mh * 4 + m4], 0, 0, 0);
      }
    }
  }

#pragma unroll
  for (int mf = 0; mf < 8; ++mf)
    *(short4v*)&po[((size_t)win * NTOK + qb + lo) * 128 + mf * 16 + hi * 4] = pk4(pacc[mf]);
}

/* ===== Fallback: proven R8 fused k_attn (182 us, bit-proven) ===== */
__global__ __launch_bounds__(512, 2) void k_attn(
    const unsigned short* __restrict__ tokbf,
    const unsigned short* __restrict__ wqkv,
    const unsigned short* __restrict__ wout,
    unsigned short* __restrict__ po) {
  __shared__ __align__(16) char smem[112128];
  unsigned short* Klds = (unsigned short*)smem;
  unsigned short* VT   = (unsigned short*)(smem + 38912);
  const int tid = threadIdx.x;
  const int wv = tid >> 6, ln = tid & 63;
  const int lo = ln & 15, hi = ln >> 4;
  const int win = blockIdx.x;
  unsigned short* QP = (unsigned short*)(smem + 73216 + wv * 4864);
  const unsigned short* tw = tokbf + (size_t)win * NTOK * DIM;
  const int qrow = wv * 32;

  f32x4 pacc[8][2];
#pragma unroll
  for (int mf = 0; mf < 8; ++mf)
#pragma unroll
    for (int nf = 0; nf < 2; ++nf) pacc[mf][nf] = (f32x4){0.f,0.f,0.f,0.f};

  for (int h = 0; h < HEADS; ++h) {
    if (h) __syncthreads();
    {
      f32x4 kacc[4][2];
#pragma unroll
      for (int mf = 0; mf < 4; ++mf)
#pragma unroll
        for (int nf = 0; nf < 2; ++nf) kacc[mf][nf] = (f32x4){0.f,0.f,0.f,0.f};
#pragma unroll
      for (int kf = 0; kf < 4; ++kf) {
        short8 aw[4], bt[2];
#pragma unroll
        for (int mf = 0; mf < 4; ++mf)
          aw[mf] = ld8_g(wqkv + (size_t)(512 + h * 64 + mf * 16 + lo) * 128 + kf * 32 + hi * 8);
#pragma unroll
        for (int nf = 0; nf < 2; ++nf)
          bt[nf] = ld8_g(&tw[(qrow + nf * 16 + lo) * 128 + kf * 32 + hi * 8]);
#pragma unroll
        for (int mf = 0; mf < 4; ++mf)
#pragma unroll
          for (int nf = 0; nf < 2; ++nf)
            kacc[mf][nf] = __builtin_amdgcn_mfma_f32_16x16x32_bf16(aw[mf], bt[nf], kacc[mf][nf], 0, 0, 0);
      }
#pragma unroll
      for (int mf = 0; mf < 4; ++mf)
#pragma unroll
        for (int nf = 0; nf < 2; ++nf)
          *(short4v*)&Klds[(qrow + nf * 16 + lo) * KPAD + mf * 16 + hi * 4] = pk4(kacc[mf][nf]);
    }
    {
      f32x4 vacc[2][4];
#pragma unroll
      for (int mf = 0; mf < 2; ++mf)
#pragma unroll
        for (int nf = 0; nf < 4; ++nf) vacc[mf][nf] = (f32x4){0.f,0.f,0.f,0.f};
#pragma unroll
      for (int kf = 0; kf < 4; ++kf) {
        short8 at[2], bw[4];
#pragma unroll
        for (int mf = 0; mf < 2; ++mf)
          at[mf] = ld8_g(&tw[(qrow + mf * 16 + lo) * 128 + kf * 32 + hi * 8]);
#pragma unroll
        for (int nf = 0; nf < 4; ++nf)
          bw[nf] = ld8_g(wqkv + (size_t)(1024 + h * 64 + nf * 16 + lo) * 128 + kf * 32 + hi * 8);
#pragma unroll
        for (int mf = 0; mf < 2; ++mf)
#pragma unroll
          for (int nf = 0; nf < 4; ++nf)
            vacc[mf][nf] = __builtin_amdgcn_mfma_f32_16x16x32_bf16(at[mf], bw[nf], vacc[mf][nf], 0, 0, 0);
      }
#pragma unroll
      for (int mf = 0; mf < 2; ++mf)
#pragma unroll
        for (int nf = 0; nf < 4; ++nf)
          *(short4v*)&VT[(nf * 16 + lo) * VPAD + qrow + mf * 16 + hi * 4] = pk4(vacc[mf][nf]);
    }
    {
      f32x4 qacc[4][2];
#pragma unroll
      for (int mf = 0; mf < 4; ++mf)
#pragma unroll
        for (int nf = 0; nf < 2; ++nf) qacc[mf][nf] = (f32x4){0.f,0.f,0.f,0.f};
#pragma unroll
      for (int kf = 0; kf < 4; ++kf) {
        short8 aw[4], bt[2];
#pragma unroll
        for (int mf = 0; mf < 4; ++mf)
          aw[mf] = ld8_g(wqkv + (size_t)(h * 64 + mf * 16 + lo) * 128 + kf * 32 + hi * 8);
#pragma unroll
        for (int nf = 0; nf < 2; ++nf)
          bt[nf] = ld8_g(&tw[(qrow + nf * 16 + lo) * 128 + kf * 32 + hi * 8]);
#pragma unroll
        for (int mf = 0; mf < 4; ++mf)
#pragma unroll
          for (int nf = 0; nf < 2; ++nf)
            qacc[mf][nf] = __builtin_amdgcn_mfma_f32_16x16x32_bf16(aw[mf], bt[nf], qacc[mf][nf], 0, 0, 0);
      }
#pragma unroll
      for (int mf = 0; mf < 4; ++mf)
#pragma unroll
        for (int nf = 0; nf < 2; ++nf)
          *(short4v*)&QP[(nf * 16 + lo) * KPAD + mf * 16 + hi * 4] = pk4(qacc[mf][nf] * 0.125f);
    }
    __syncthreads();

    short8 Qb[2][2];
#pragma unroll
    for (int nf = 0; nf < 2; ++nf)
#pragma unroll
      for (int kf = 0; kf < 2; ++kf)
        Qb[nf][kf] = ld8_lds(&QP[(nf * 16 + lo) * KPAD + kf * 32 + hi * 8]);

    f32x4 Ot[4][2];
#pragma unroll
    for (int mf = 0; mf < 4; ++mf)
#pragma unroll
      for (int nf = 0; nf < 2; ++nf) Ot[mf][nf] = (f32x4){0.f,0.f,0.f,0.f};
    float mrow[2] = {-INFINITY, -INFINITY};
    float lrow[2] = {0.f, 0.f};

    for (int ck = 0; ck < 4; ++ck) {
      f32x4 sacc[4][2];
#pragma unroll
      for (int mf = 0; mf < 4; ++mf)
#pragma unroll
        for (int nf = 0; nf < 2; ++nf) sacc[mf][nf] = (f32x4){0.f,0.f,0.f,0.f};
      short8 ka[4][2];
#pragma unroll
      for (int mf = 0; mf < 4; ++mf)
#pragma unroll
        for (int kf = 0; kf < 2; ++kf)
          ka[mf][kf] = ld8_lds(&Klds[(ck * 64 + mf * 16 + lo) * KPAD + kf * 32 + hi * 8]);
#pragma unroll
      for (int mf = 0; mf < 4; ++mf)
#pragma unroll
        for (int nf = 0; nf < 2; ++nf)
#pragma unroll
          for (int kf = 0; kf < 2; ++kf)
            sacc[mf][nf] = __builtin_amdgcn_mfma_f32_16x16x32_bf16(ka[mf][kf], Qb[nf][kf], sacc[mf][nf], 0, 0, 0);

#pragma unroll
      for (int nf = 0; nf < 2; ++nf) {
        float cmax = -INFINITY;
#pragma unroll
        for (int mf = 0; mf < 4; ++mf)
#pragma unroll
          for (int r = 0; r < 4; ++r) cmax = fmaxf(cmax, sacc[mf][nf][r]);
        cmax = fmaxf(cmax, __shfl_xor(cmax, 16));
        cmax = fmaxf(cmax, __shfl_xor(cmax, 32));
        float mnew = fmaxf(mrow[nf], cmax);
        float corr = __expf(mrow[nf] - mnew);
        float ps = 0.f;
#pragma unroll
        for (int mf = 0; mf < 4; ++mf)
#pragma unroll
          for (int r = 0; r < 4; ++r) {
            float e = __expf(sacc[mf][nf][r] - mnew);
            sacc[mf][nf][r] = e; ps += e;
          }
        ps += __shfl_xor(ps, 16);
        ps += __shfl_xor(ps, 32);
        lrow[nf] = lrow[nf] * corr + ps;
        mrow[nf] = mnew;
#pragma unroll
        for (int mf = 0; mf < 4; ++mf) Ot[mf][nf] *= corr;
      }
#pragma unroll
      for (int mf = 0; mf < 4; ++mf)
#pragma unroll
        for (int nf = 0; nf < 2; ++nf)
          *(short4v*)&QP[(nf * 16 + lo) * KPAD + mf * 16 + hi * 4] = pk4(sacc[mf][nf]);
      short8 pb[2][2], va[4][2];
#pragma unroll
      for (int nf = 0; nf < 2; ++nf)
#pragma unroll
        for (int kf = 0; kf < 2; ++kf)
          pb[nf][kf] = ld8_lds(&QP[(nf * 16 + lo) * KPAD + kf * 32 + hi * 8]);
#pragma unroll
      for (int mf = 0; mf < 4; ++mf)
#pragma unroll
        for (int kf = 0; kf < 2; ++kf)
          va[mf][kf] = ld8_lds(&VT[(mf * 16 + lo) * VPAD + ck * 64 + kf * 32 + hi * 8]);
#pragma unroll
      for (int mf = 0; mf < 4; ++mf)
#pragma unroll
        for (int nf = 0; nf < 2; ++nf)
#pragma unroll
          for (int kf = 0; kf < 2; ++kf)
            Ot[mf][nf] = __builtin_amdgcn_mfma_f32_16x16x32_bf16(va[mf][kf], pb[nf][kf], Ot[mf][nf], 0, 0, 0);
    }

#pragma unroll
    for (int nf = 0; nf < 2; ++nf) {
      float inv = 1.f / lrow[nf];
#pragma unroll
      for (int mf = 0; mf < 4; ++mf)
        *(short4v*)&QP[(nf * 16 + lo) * KPAD + mf * 16 + hi * 4] = pk4(Ot[mf][nf] * inv);
    }
    short8 Ob[2][2];
#pragma unroll
    for (int nf = 0; nf < 2; ++nf)
#pragma unroll
      for (int kf = 0; kf < 2; ++kf)
        Ob[nf][kf] = ld8_lds(&QP[(nf * 16 + lo) * KPAD + kf * 32 + hi * 8]);
#pragma unroll
    for (int kf = 0; kf < 2; ++kf) {
      short8 aw[8];
#pragma unroll
      for (int mf = 0; mf < 8; ++mf)
        aw[mf] = ld8_g(wout + (size_t)(mf * 16 + lo) * 512 + h * 64 + kf * 32 + hi * 8);
#pragma unroll
      for (int mf = 0; mf < 8; ++mf)
#pragma unroll
        for (int nf = 0; nf < 2; ++nf)
          pacc[mf][nf] = __builtin_amdgcn_mfma_f32_16x16x32_bf16(aw[mf], Ob[nf][kf], pacc[mf][nf], 0, 0, 0);
    }
  }
#pragma unroll
  for (int mf = 0; mf < 8; ++mf)
#pragma unroll
    for (int nf = 0; nf < 2; ++nf)
      *(short4v*)&po[((size_t)win * NTOK + qrow + nf * 16 + lo) * 128 + mf * 16 + hi * 4] = pk4(pacc[mf][nf]);
}

/* Gather finalize (proven). */
__global__ void k_final(const float* __restrict__ x, const unsigned short* __restrict__ po,
                        const int* __restrict__ keep, const float* __restrict__ bout,
                        float* __restrict__ out) {
  __shared__ int kp[2 * NKEEP];
  int tid = threadIdx.x;
  int gid = blockIdx.x * 256 + tid;
  int chq = gid & 3, pix = gid >> 2;
  int b = pix >> 16, pb = pix & 65535, y = pb >> 8, xx = pb & 255;
  if (tid < 2 * NKEEP) kp[tid] = keep[b * 2 * NKEEP + tid];
  __syncthreads();
  float acc[32];
#pragma unroll
  for (int i = 0; i < 32; ++i) acc[i] = 0.f;
  float cnt = 0.f;
  for (int w = 0; w < NKEEP; ++w) {
    int dy = y - kp[2 * w], dx = xx - kp[2 * w + 1];
    if ((unsigned)dy < 16u && (unsigned)dx < 16u) {
      cnt += 1.f;
      const unsigned short* pp = po + ((size_t)(b * NKEEP + w) * NTOK + dy * 16 + dx) * 128 + chq * 32;
#pragma unroll
      for (int k2 = 0; k2 < 4; ++k2) {
        short8 v = ld8_g(pp + k2 * 8);
#pragma unroll
        for (int j = 0; j < 8; ++j) {
          union { unsigned u; float f; } cv;
          cv.u = ((unsigned)(unsigned short)v[j]) << 16;
          acc[k2 * 8 + j] += cv.f;
        }
      }
    }
  }
  size_t base = (size_t)pix * 128 + chq * 32;
  float inv = 1.f / (cnt + 1e-10f);
#pragma unroll
  for (int i = 0; i < 32; ++i)
    out[base + i] = x[base + i] + (acc[i] + cnt * bout[chq * 32 + i]) * inv;
}

extern "C" void kernel_launch(void* const* d_in, const int* in_sizes, int n_in,
                              void* d_out, int out_size, void* d_ws, size_t ws_size,
                              hipStream_t stream) {
  const float* x    = (const float*)d_in[0];
  const float* prob = (const float*)d_in[1];
  const float* fixw = (const float*)d_in[2];
  const float* wqkv = (const float*)d_in[3];
  const float* wout = (const float*)d_in[4];
  const float* bout = (const float*)d_in[5];
  float* out = (float*)d_out;
  float* ws  = (float*)d_ws;
  if (ws_size < (size_t)WS_FLOATS * 4) return;  /* need >= 27.3 MB */

  float* ent  = ws + OFF_ENT;
  float* scp  = ws + OFF_SCORE;
  int*   keep = (int*)(ws + OFF_KEEP);
  unsigned short* wqkv_bf = (unsigned short*)(ws + OFF_WQKV);
  unsigned short* wout_bf = (unsigned short*)(ws + OFF_WOUT);
  unsigned short* tokbf   = (unsigned short*)(ws + OFF_TOKBF);
  unsigned short* po      = (unsigned short*)(ws + OFF_PO);

  /* Deterministic host-side check: use the q-split kernel only if the
     compiler kept it spill-free within the 128-VGPR 2-blocks/CU budget. */
  hipFuncAttributes fa;
  int use3 = 0;
  if (hipFuncGetAttributes(&fa, (const void*)k_attn3) == hipSuccess)
    use3 = (fa.numRegs > 0 && fa.numRegs <= 128 && fa.localSizeBytes == 0);

  k_entropy<<<256, 256, 0, stream>>>(prob, ent);
  k_score<<<(NB * SCPAD + 255) / 256, 256, 0, stream>>>(ent, fixw, scp);
  k_wcvt<<<1024, 256, 0, stream>>>(wqkv, wout, wqkv_bf, wout_bf);
  k_nms<<<NB, 64, 0, stream>>>(scp, keep);
  k_toks<<<NWTOT, 256, 0, stream>>>(x, keep, tokbf);
  if (use3)
    k_attn3<<<NWTOT * 2, 512, 0, stream>>>(tokbf, wqkv_bf, wout_bf, po);
  else
    k_attn<<<NWTOT, 512, 0, stream>>>(tokbf, wqkv_bf, wout_bf, po);
  k_final<<<NB * 65536 * 4 / 256, 256, 0, stream>>>(x, po, keep, bout, out);
}